// Round 1
// baseline (6692.228 us; speedup 1.0000x reference)
//
#include <hip/hip_runtime.h>
#include <cstdint>
#include <cstddef>

#define NNODES 131072
#define NEDGES 1048576
#define NPROB  64

constexpr int TN = 32;   // node tile per block for GEMM/GRU kernels

__device__ __forceinline__ float sigm(float x) { return 1.0f / (1.0f + expf(-x)); }

// ---------------- transpose [384][128] -> [128][384] ----------------
__global__ __launch_bounds__(256) void transpose_w(const float* __restrict__ in,
                                                   float* __restrict__ outp)
{
    int idx = blockIdx.x * 256 + threadIdx.x;
    if (idx < 384 * 128) {
        int j = idx >> 7;      // 0..383 (row of Wih)
        int k = idx & 127;     // 0..127
        outp[k * 384 + j] = in[idx];
    }
}

// ---------------- emb1: Y = relu(G @ W1 + b1), G [N,8] ----------------
__global__ __launch_bounds__(256) void emb1_kernel(const float* __restrict__ G,
    const float* __restrict__ W1, const float* __restrict__ b1, float* __restrict__ Y)
{
    int idx = blockIdx.x * 256 + threadIdx.x;   // (n, c)
    int n = idx >> 7, c = idx & 127;
    const float* g = G + (size_t)n * 8;
    float y = b1[c];
#pragma unroll
    for (int k = 0; k < 8; ++k) y = fmaf(g[k], W1[k * 128 + c], y);
    Y[(size_t)n * 128 + c] = fmaxf(y, 0.0f);
}

// ---------------- generic node GEMM: Y = act(X@W + bias [+ segadd[seg[n]]]) ----
// X [N,K] row-major, W [K][M] row-major (row stride == M), Y [N,M].
template<int K, int M, bool RELU, bool SEGADD>
__global__ __launch_bounds__(256) void gemm_node(const float* __restrict__ X,
    const float* __restrict__ W, const float* __restrict__ bias,
    const float* __restrict__ segadd, const int* __restrict__ seg,
    float* __restrict__ Y)
{
    __shared__ float xs[TN][K];        // 16KB (K=128) / 32KB (K=256)
    __shared__ float wsm[64][128];     // 32KB W chunk
    const int tid = threadIdx.x;
    const int nbase = blockIdx.x * TN;

    for (int i = tid; i < TN * (K / 4); i += 256) {
        int r = i / (K / 4), c = i % (K / 4);
        ((float4*)&xs[r][0])[c] = ((const float4*)(X + (size_t)(nbase + r) * K))[c];
    }

    const int cg = tid & 31;   // 4-col group
    const int ng = tid >> 5;   // 4-node group
    float acc[4][4];

    for (int mc = 0; mc < M; mc += 128) {
#pragma unroll
        for (int i = 0; i < 4; ++i)
#pragma unroll
            for (int j = 0; j < 4; ++j) acc[i][j] = 0.0f;

        for (int kc = 0; kc < K; kc += 64) {
            __syncthreads();   // protect previous wsm use (and xs staging first time)
            for (int i = tid; i < 64 * 32; i += 256) {
                int r = i >> 5, c4 = i & 31;
                ((float4*)&wsm[r][0])[c4] =
                    ((const float4*)(W + (size_t)(kc + r) * M + mc))[c4];
            }
            __syncthreads();
#pragma unroll 16
            for (int k = 0; k < 64; ++k) {
                float4 wv = ((const float4*)&wsm[k][0])[cg];
                float xv[4];
#pragma unroll
                for (int i = 0; i < 4; ++i) xv[i] = xs[ng * 4 + i][kc + k];
#pragma unroll
                for (int i = 0; i < 4; ++i) {
                    acc[i][0] = fmaf(xv[i], wv.x, acc[i][0]);
                    acc[i][1] = fmaf(xv[i], wv.y, acc[i][1]);
                    acc[i][2] = fmaf(xv[i], wv.z, acc[i][2]);
                    acc[i][3] = fmaf(xv[i], wv.w, acc[i][3]);
                }
            }
        }

        // epilogue for this 128-col chunk
        float4 bv = make_float4(0.f, 0.f, 0.f, 0.f);
        if (bias) bv = ((const float4*)(bias + mc))[cg];
#pragma unroll
        for (int i = 0; i < 4; ++i) {
            int n = nbase + ng * 4 + i;
            float o0 = acc[i][0] + bv.x;
            float o1 = acc[i][1] + bv.y;
            float o2 = acc[i][2] + bv.z;
            float o3 = acc[i][3] + bv.w;
            if (SEGADD) {
                int p = seg[n];
                float4 sv = ((const float4*)(segadd + (size_t)p * M + mc))[cg];
                o0 += sv.x; o1 += sv.y; o2 += sv.z; o3 += sv.w;
            }
            if (RELU) {
                o0 = fmaxf(o0, 0.f); o1 = fmaxf(o1, 0.f);
                o2 = fmaxf(o2, 0.f); o3 = fmaxf(o3, 0.f);
            }
            ((float4*)(Y + (size_t)n * M + mc))[cg] = make_float4(o0, o1, o2, o3);
        }
    }
}

// ---------------- fused GRU cell: h = GRUCell(agg, h) (in-place) ----------------
// WihT/WhhT are [128][384] (pre-transposed). Optional relu on output.
__global__ __launch_bounds__(256) void gru_kernel(const float* __restrict__ agg,
    float* __restrict__ h, const float* __restrict__ WihT, const float* __restrict__ WhhT,
    const float* __restrict__ bih, const float* __restrict__ bhh, int relu_out)
{
    __shared__ float as[TN][128];   // 16KB
    __shared__ float hs[TN][128];   // 16KB
    __shared__ float wsm[64][128];  // 32KB
    const int tid = threadIdx.x;
    const int nbase = blockIdx.x * TN;

    for (int i = tid; i < TN * 32; i += 256) {
        int r = i >> 5, c = i & 31;
        ((float4*)&as[r][0])[c] = ((const float4*)(agg + (size_t)(nbase + r) * 128))[c];
        ((float4*)&hs[r][0])[c] = ((const float4*)(h + (size_t)(nbase + r) * 128))[c];
    }

    const int cg = tid & 31, ng = tid >> 5;
    float rg[4][4], zg[4][4];

    for (int g = 0; g < 3; ++g) {
        float aI[4][4], aH[4][4];
#pragma unroll
        for (int i = 0; i < 4; ++i)
#pragma unroll
            for (int j = 0; j < 4; ++j) { aI[i][j] = 0.f; aH[i][j] = 0.f; }

        // input-side gate GEMM: agg @ WihT[:, g*128 .. +128]
        for (int kc = 0; kc < 128; kc += 64) {
            __syncthreads();
            for (int i = tid; i < 64 * 32; i += 256) {
                int r = i >> 5, c4 = i & 31;
                ((float4*)&wsm[r][0])[c4] =
                    ((const float4*)(WihT + (size_t)(kc + r) * 384 + g * 128))[c4];
            }
            __syncthreads();
#pragma unroll 16
            for (int k = 0; k < 64; ++k) {
                float4 wv = ((const float4*)&wsm[k][0])[cg];
                float xv[4];
#pragma unroll
                for (int i = 0; i < 4; ++i) xv[i] = as[ng * 4 + i][kc + k];
#pragma unroll
                for (int i = 0; i < 4; ++i) {
                    aI[i][0] = fmaf(xv[i], wv.x, aI[i][0]);
                    aI[i][1] = fmaf(xv[i], wv.y, aI[i][1]);
                    aI[i][2] = fmaf(xv[i], wv.z, aI[i][2]);
                    aI[i][3] = fmaf(xv[i], wv.w, aI[i][3]);
                }
            }
        }
        // hidden-side gate GEMM: h @ WhhT[:, g*128 .. +128]
        for (int kc = 0; kc < 128; kc += 64) {
            __syncthreads();
            for (int i = tid; i < 64 * 32; i += 256) {
                int r = i >> 5, c4 = i & 31;
                ((float4*)&wsm[r][0])[c4] =
                    ((const float4*)(WhhT + (size_t)(kc + r) * 384 + g * 128))[c4];
            }
            __syncthreads();
#pragma unroll 16
            for (int k = 0; k < 64; ++k) {
                float4 wv = ((const float4*)&wsm[k][0])[cg];
                float xv[4];
#pragma unroll
                for (int i = 0; i < 4; ++i) xv[i] = hs[ng * 4 + i][kc + k];
#pragma unroll
                for (int i = 0; i < 4; ++i) {
                    aH[i][0] = fmaf(xv[i], wv.x, aH[i][0]);
                    aH[i][1] = fmaf(xv[i], wv.y, aH[i][1]);
                    aH[i][2] = fmaf(xv[i], wv.z, aH[i][2]);
                    aH[i][3] = fmaf(xv[i], wv.w, aH[i][3]);
                }
            }
        }

        float4 bi = ((const float4*)(bih + g * 128))[cg];
        float4 bh = ((const float4*)(bhh + g * 128))[cg];
        float bia[4] = { bi.x, bi.y, bi.z, bi.w };
        float bha[4] = { bh.x, bh.y, bh.z, bh.w };

        if (g == 0) {
#pragma unroll
            for (int i = 0; i < 4; ++i)
#pragma unroll
                for (int j = 0; j < 4; ++j)
                    rg[i][j] = sigm(aI[i][j] + bia[j] + aH[i][j] + bha[j]);
        } else if (g == 1) {
#pragma unroll
            for (int i = 0; i < 4; ++i)
#pragma unroll
                for (int j = 0; j < 4; ++j)
                    zg[i][j] = sigm(aI[i][j] + bia[j] + aH[i][j] + bha[j]);
        } else {
#pragma unroll
            for (int i = 0; i < 4; ++i) {
                int n = nbase + ng * 4 + i;
                float out[4];
#pragma unroll
                for (int j = 0; j < 4; ++j) {
                    float nv = tanhf(aI[i][j] + bia[j] + rg[i][j] * (aH[i][j] + bha[j]));
                    float hold = hs[ng * 4 + i][cg * 4 + j];
                    float hn = (1.0f - zg[i][j]) * nv + zg[i][j] * hold;
                    out[j] = relu_out ? fmaxf(hn, 0.0f) : hn;
                }
                ((float4*)(h + (size_t)n * 128))[cg] =
                    make_float4(out[0], out[1], out[2], out[3]);
            }
        }
    }
}

// ---------------- edge gather + scatter-add: agg[dst] += t[src] * ew ----------------
__global__ __launch_bounds__(256) void edge_scatter(const float* __restrict__ t,
    const int* __restrict__ src, const int* __restrict__ dst,
    const float* __restrict__ ew, float* __restrict__ agg)
{
    int slot = blockIdx.x * 2 + (threadIdx.x >> 7);   // edge index
    int c = threadIdx.x & 127;
    int s = src[slot], d = dst[slot];
    float w = ew[slot];
    atomicAdd(agg + (size_t)d * 128 + c, t[(size_t)s * 128 + c] * w);
}

// ---------------- segment sums + counts ----------------
__global__ __launch_bounds__(256) void seg_sum(const float* __restrict__ x,
    const int* __restrict__ seg, float* __restrict__ sums, float* __restrict__ counts)
{
    int idx = blockIdx.x * 256 + threadIdx.x;
    int n = idx >> 7, c = idx & 127;
    int p = seg[n];
    atomicAdd(sums + (size_t)p * 128 + c, x[(size_t)n * 128 + c]);
    if (c == 0) atomicAdd(counts + p, 1.0f);
}

// ---------------- gproj[p] = gmean[p] @ W_l[128:256,:] + b_l ----------------
__global__ __launch_bounds__(256) void gproj_kernel(const float* __restrict__ sums,
    const float* __restrict__ counts, const float* __restrict__ Wl,
    const float* __restrict__ bl, float* __restrict__ gproj)
{
    __shared__ float gm[128];
    int p = blockIdx.x, m = threadIdx.x;
    if (m < 128) gm[m] = sums[(size_t)p * 128 + m] / fmaxf(counts[p], 1.0f);
    __syncthreads();
    float acc = bl[m];
#pragma unroll 8
    for (int k = 0; k < 128; ++k)
        acc = fmaf(gm[k], Wl[(size_t)(128 + k) * 256 + m], acc);
    gproj[(size_t)p * 256 + m] = acc;
}

// ---------------- final: out[n] = u2[n] . W_l3 + b_l3 ----------------
__global__ __launch_bounds__(256) void final_dot(const float* __restrict__ u2,
    const float* __restrict__ wl3, const float* __restrict__ bl3, float* __restrict__ out)
{
    int gid = blockIdx.x * 256 + threadIdx.x;
    int n = gid >> 6, lane = gid & 63;
    const float* row = u2 + (size_t)n * 128;
    float s = fmaf(row[lane], wl3[lane], row[lane + 64] * wl3[lane + 64]);
#pragma unroll
    for (int off = 32; off; off >>= 1) s += __shfl_xor(s, off);
    if (lane == 0) out[n] = s + bl3[0];
}

extern "C" void kernel_launch(void* const* d_in, const int* in_sizes, int n_in,
                              void* d_out, int out_size, void* d_ws, size_t ws_size,
                              hipStream_t stream)
{
    (void)in_sizes; (void)n_in; (void)out_size; (void)ws_size;

    const float* G     = (const float*)d_in[0];
    const int*   ei    = (const int*)d_in[1];
    const float* ew    = (const float*)d_in[2];
    const int*   seg   = (const int*)d_in[4];
    const float* Wemb1 = (const float*)d_in[5];  const float* bemb1 = (const float*)d_in[6];
    const float* Wemb2 = (const float*)d_in[7];  const float* bemb2 = (const float*)d_in[8];
    const float* c1W   = (const float*)d_in[9];
    const float* c1Wih = (const float*)d_in[10]; const float* c1Whh = (const float*)d_in[11];
    const float* c1bih = (const float*)d_in[12]; const float* c1bhh = (const float*)d_in[13];
    const float* c2W   = (const float*)d_in[14];
    const float* c2Wih = (const float*)d_in[15]; const float* c2Whh = (const float*)d_in[16];
    const float* c2bih = (const float*)d_in[17]; const float* c2bhh = (const float*)d_in[18];
    const float* Wg1   = (const float*)d_in[19]; const float* bg1   = (const float*)d_in[20];
    const float* Wg2   = (const float*)d_in[21]; const float* bg2   = (const float*)d_in[22];
    const float* Wl    = (const float*)d_in[23]; const float* bl    = (const float*)d_in[24];
    const float* Wl2   = (const float*)d_in[25]; const float* bl2   = (const float*)d_in[26];
    const float* Wl3   = (const float*)d_in[27]; const float* bl3   = (const float*)d_in[28];

    const int* srcp = ei;
    const int* dstp = ei + NEDGES;

    char* ws = (char*)d_ws;
    const size_t NB = (size_t)NNODES * 128 * 4;   // 64 MB per node buffer
    float* A      = (float*)ws;                    // current h / x
    float* B      = (float*)(ws + NB);             // t / tmp (u1 spans B..C)
    float* C      = (float*)(ws + 2 * NB);         // agg
    float* sums   = (float*)(ws + 3 * NB);
    float* counts = (float*)(ws + 3 * NB + 64 * 128 * 4);
    float* gproj  = (float*)(ws + 3 * NB + 64 * 128 * 4 + 1024);
    float* wT     = (float*)(ws + 3 * NB + 64 * 128 * 4 + 1024 + 64 * 256 * 4);
    float* Wih1T  = wT;
    float* Whh1T  = wT + 128 * 384;
    float* Wih2T  = wT + 2 * 128 * 384;
    float* Whh2T  = wT + 3 * 128 * 384;

    // transpose GRU weights once per call
    transpose_w<<<192, 256, 0, stream>>>(c1Wih, Wih1T);
    transpose_w<<<192, 256, 0, stream>>>(c1Whh, Whh1T);
    transpose_w<<<192, 256, 0, stream>>>(c2Wih, Wih2T);
    transpose_w<<<192, 256, 0, stream>>>(c2Whh, Whh2T);

    const int GG = NNODES / TN;   // 4096 blocks

    // embeddings
    emb1_kernel<<<NNODES * 128 / 256, 256, 0, stream>>>(G, Wemb1, bemb1, B);
    gemm_node<128, 128, true, false><<<GG, 256, 0, stream>>>(B, Wemb2, bemb2, nullptr, nullptr, A);

    // two GatedGraphConv layers, 2 GRU iterations each
    const float* convW[2] = { c1W, c2W };
    const float* WihTs[2] = { Wih1T, Wih2T };
    const float* WhhTs[2] = { Whh1T, Whh2T };
    const float* bihs[2]  = { c1bih, c2bih };
    const float* bhhs[2]  = { c1bhh, c2bhh };
    for (int cv = 0; cv < 2; ++cv) {
        for (int l = 0; l < 2; ++l) {
            gemm_node<128, 128, false, false><<<GG, 256, 0, stream>>>(
                A, convW[cv] + (size_t)l * 128 * 128, nullptr, nullptr, nullptr, B);
            hipMemsetAsync(C, 0, NB, stream);
            edge_scatter<<<NEDGES / 2, 256, 0, stream>>>(B, srcp, dstp, ew, C);
            gru_kernel<<<GG, 256, 0, stream>>>(C, A, WihTs[cv], WhhTs[cv],
                                               bihs[cv], bhhs[cv], (l == 1) ? 1 : 0);
        }
    }

    // head MLP
    gemm_node<128, 128, true, false><<<GG, 256, 0, stream>>>(A, Wg1, bg1, nullptr, nullptr, B);
    gemm_node<128, 128, false, false><<<GG, 256, 0, stream>>>(B, Wg2, bg2, nullptr, nullptr, A);

    // segment mean -> projected through bottom half of W_l (+ b_l)
    hipMemsetAsync(sums, 0, 64 * 128 * 4 + 1024, stream);   // sums + counts
    seg_sum<<<NNODES * 128 / 256, 256, 0, stream>>>(A, seg, sums, counts);
    gproj_kernel<<<NPROB, 256, 0, stream>>>(sums, counts, Wl, bl, gproj);

    // u1 = relu(x @ Wl_top + gproj[seg])  [N,256] -> spans B..C
    gemm_node<128, 256, true, true><<<GG, 256, 0, stream>>>(A, Wl, nullptr, gproj, seg, B);
    // u2 = relu(u1 @ W_l2 + b_l2) [N,128]
    gemm_node<256, 128, true, false><<<GG, 256, 0, stream>>>(B, Wl2, bl2, nullptr, nullptr, A);
    // out = u2 @ W_l3 + b_l3
    final_dot<<<NNODES * 64 / 256, 256, 0, stream>>>(A, Wl3, bl3, (float*)d_out);
}

// Round 2
// 5250.090 us; speedup vs baseline: 1.2747x; 1.2747x over previous
//
#include <hip/hip_runtime.h>
#include <cstdint>
#include <cstddef>

#define NNODES 131072
#define NEDGES 1048576
#define NPROB  64

typedef _Float16 half8 __attribute__((ext_vector_type(8)));
typedef _Float16 half4v __attribute__((ext_vector_type(4)));
typedef _Float16 half2v __attribute__((ext_vector_type(2)));
typedef float float4v __attribute__((ext_vector_type(4)));

__device__ __forceinline__ float sigm(float x) { return 1.0f / (1.0f + expf(-x)); }

__device__ __forceinline__ void async16(void* lds, const void* g) {
    __builtin_amdgcn_global_load_lds(
        (const __attribute__((address_space(1))) uint32_t*)g,
        (__attribute__((address_space(3))) uint32_t*)lds, 16, 0, 0);
}

// ---------------- weight prep: fp32 -> fp16 (optionally transposed) ----------------
__global__ __launch_bounds__(256) void cvt16(const float* __restrict__ s,
                                             _Float16* __restrict__ d, int n)
{
    int i = blockIdx.x * 256 + threadIdx.x;
    if (i < n) d[i] = (_Float16)s[i];
}

// dst[m*K + k] = src[k*sstride + m]   (dst is [M][K] fp16)
__global__ __launch_bounds__(256) void tr_cvt(const float* __restrict__ src,
    _Float16* __restrict__ dst, int K, int M, int sstride)
{
    int i = blockIdx.x * 256 + threadIdx.x;
    if (i < M * K) {
        int m = i / K, k = i % K;
        dst[i] = (_Float16)src[(size_t)k * sstride + m];
    }
}

// ---------------- emb1: x = relu(G @ W1 + b1) -> fp16 ----------------
__global__ __launch_bounds__(256) void emb1_kernel(const float* __restrict__ G,
    const float* __restrict__ W1, const float* __restrict__ b1, _Float16* __restrict__ Y)
{
    int idx = blockIdx.x * 256 + threadIdx.x;
    int n = idx >> 7, c = idx & 127;
    const float* g = G + (size_t)n * 8;
    float y = b1[c];
#pragma unroll
    for (int k = 0; k < 8; ++k) y = fmaf(g[k], W1[k * 128 + c], y);
    Y[(size_t)n * 128 + c] = (_Float16)fmaxf(y, 0.0f);
}

// ---------------- MFMA GEMM: out = act(X @ WtT + bias [+gproj]) ----------------
// Wt is [M][K] fp16 (pre-transposed). X tile: 128 nodes. 4 waves, wave w owns rows
// [w*32, w*32+32). W frags held in registers (hoisted per m-chunk). LDS XOR-swizzled.
// OM: 0 = plain write (out1, stride ostride); 1 = GH mode (mc<2: accumulate into
// out1 [N][384]; mc==2: plain write to out2 [N][128]).
template<int K, int MCH, bool INF16, int OM, bool RELU, bool SEGADD>
__global__ __launch_bounds__(256, 2) void gemm_mfma(
    const void* __restrict__ Xin, int xstride,
    const _Float16* __restrict__ Wt,
    const float* __restrict__ bias,
    _Float16* __restrict__ out1, int ostride,
    _Float16* __restrict__ out2,
    const float* __restrict__ gproj, const int* __restrict__ seg)
{
    constexpr int ROWB = 2 * K;     // LDS row bytes
    constexpr int SPR  = K / 8;     // 16B slots per row
    __shared__ __align__(16) char Xs[128 * ROWB];
    __shared__ __align__(16) char Ws[128 * ROWB];
    const int tid = threadIdx.x, wid = tid >> 6, l = tid & 63;
    const int lr = l & 15, lk = l >> 4;
    const int wrow = wid * 32;

    for (int mc = 0; mc < MCH; ++mc) {
        __syncthreads();   // all waves done with previous Ws/Xs
        {   // stage W chunk [128][K] (swizzled via pre-permuted source)
            const _Float16* wsrc = Wt + (size_t)mc * 128 * K;
            for (int s0 = wid * 64; s0 < 128 * SPR; s0 += 256) {
                int s = s0 + l;
                int row = s / SPR, sub = s % SPR;
                int ksub = sub ^ (row & 7);
                async16(Ws + s0 * 16, (const char*)(wsrc + (size_t)row * K) + ksub * 16);
            }
        }
        asm volatile("s_waitcnt vmcnt(0)" ::: "memory");
        __syncthreads();

        half8 bfr[32];
        if constexpr (K == 128) {
#pragma unroll
            for (int ct = 0; ct < 8; ++ct)
#pragma unroll
                for (int ks = 0; ks < 4; ++ks) {
                    int row = ct * 16 + lr;
                    bfr[ct * 4 + ks] = *(const half8*)(Ws + row * ROWB +
                        ((ks * 64 + lk * 16) ^ ((row & 7) << 4)));
                }
        }

        for (int t = blockIdx.x; t < NNODES / 128; t += gridDim.x) {
            const int nbase = t * 128;
            __syncthreads();   // previous tile's reads complete before overwrite
            if constexpr (INF16) {
                const _Float16* xsrc = (const _Float16*)Xin;
                for (int s0 = wid * 64; s0 < 128 * SPR; s0 += 256) {
                    int s = s0 + l;
                    int row = s / SPR, sub = s % SPR;
                    int ksub = sub ^ (row & 7);
                    async16(Xs + s0 * 16,
                            (const char*)(xsrc + (size_t)(nbase + row) * xstride) + ksub * 16);
                }
                asm volatile("s_waitcnt vmcnt(0)" ::: "memory");
            } else {
                const float* xsrc = (const float*)Xin;
                for (int s = tid; s < 128 * SPR; s += 256) {
                    int row = s / SPR, sub = s % SPR;
                    int ksub = sub ^ (row & 7);
                    const float* p = xsrc + (size_t)(nbase + row) * xstride + ksub * 8;
                    float4 u = ((const float4*)p)[0];
                    float4 v = ((const float4*)p)[1];
                    half8 hv;
                    hv[0] = (_Float16)u.x; hv[1] = (_Float16)u.y;
                    hv[2] = (_Float16)u.z; hv[3] = (_Float16)u.w;
                    hv[4] = (_Float16)v.x; hv[5] = (_Float16)v.y;
                    hv[6] = (_Float16)v.z; hv[7] = (_Float16)v.w;
                    *(half8*)(Xs + s * 16) = hv;
                }
            }
            __syncthreads();

            float4v acc[2][8];
#pragma unroll
            for (int i = 0; i < 2; ++i)
#pragma unroll
                for (int j = 0; j < 8; ++j)
#pragma unroll
                    for (int q = 0; q < 4; ++q) acc[i][j][q] = 0.0f;

            if constexpr (K == 128) {
#pragma unroll
                for (int rt = 0; rt < 2; ++rt) {
                    half8 a[4];
                    int row = wrow + rt * 16 + lr;
#pragma unroll
                    for (int ks = 0; ks < 4; ++ks)
                        a[ks] = *(const half8*)(Xs + row * ROWB +
                            ((ks * 64 + lk * 16) ^ ((row & 7) << 4)));
#pragma unroll
                    for (int ct = 0; ct < 8; ++ct)
#pragma unroll
                        for (int ks = 0; ks < 4; ++ks)
                            acc[rt][ct] = __builtin_amdgcn_mfma_f32_16x16x32_f16(
                                a[ks], bfr[ct * 4 + ks], acc[rt][ct], 0, 0, 0);
                }
            } else {   // K == 256: frags reloaded per k-half
#pragma unroll
                for (int kc = 0; kc < 2; ++kc) {
#pragma unroll
                    for (int ct = 0; ct < 8; ++ct)
#pragma unroll
                        for (int ks = 0; ks < 4; ++ks) {
                            int row = ct * 16 + lr;
                            bfr[ct * 4 + ks] = *(const half8*)(Ws + row * ROWB +
                                (((kc * 4 + ks) * 64 + lk * 16) ^ ((row & 7) << 4)));
                        }
#pragma unroll
                    for (int rt = 0; rt < 2; ++rt) {
                        half8 a[4];
                        int row = wrow + rt * 16 + lr;
#pragma unroll
                        for (int ks = 0; ks < 4; ++ks)
                            a[ks] = *(const half8*)(Xs + row * ROWB +
                                (((kc * 4 + ks) * 64 + lk * 16) ^ ((row & 7) << 4)));
#pragma unroll
                        for (int ct = 0; ct < 8; ++ct)
#pragma unroll
                            for (int ks = 0; ks < 4; ++ks)
                                acc[rt][ct] = __builtin_amdgcn_mfma_f32_16x16x32_f16(
                                    a[ks], bfr[ct * 4 + ks], acc[rt][ct], 0, 0, 0);
                    }
                }
            }

            // epilogue: C/D layout col = lane&15, row = (lane>>4)*4 + j
#pragma unroll
            for (int rt = 0; rt < 2; ++rt)
#pragma unroll
            for (int ct = 0; ct < 8; ++ct) {
                const int col = ct * 16 + lr;
                float bv = 0.0f;
                if (bias) bv = bias[mc * 128 + col];
#pragma unroll
                for (int j = 0; j < 4; ++j) {
                    const int n = nbase + wrow + rt * 16 + lk * 4 + j;
                    float v = acc[rt][ct][j] + bv;
                    if constexpr (SEGADD)
                        v += gproj[(size_t)seg[n] * 256 + mc * 128 + col];
                    if constexpr (OM == 1) {
                        if (mc < 2) {
                            size_t o = (size_t)n * ostride + mc * 128 + col;
                            out1[o] = (_Float16)(v + (float)out1[o]);
                        } else {
                            out2[(size_t)n * 128 + col] = (_Float16)v;
                        }
                    } else {
                        if constexpr (RELU) v = fmaxf(v, 0.0f);
                        out1[(size_t)n * ostride + mc * 128 + col] = (_Float16)v;
                    }
                }
            }
        }
    }
}

// ---------------- GRU combine: h' = (1-z)*tanh(in+r*hn) + z*h ----------------
__global__ __launch_bounds__(256) void gru_combine(const _Float16* __restrict__ g,
    const _Float16* __restrict__ gn, _Float16* __restrict__ h,
    const float* __restrict__ bih, const float* __restrict__ bhh, int relu_out)
{
    int idx = blockIdx.x * 256 + threadIdx.x;   // N*16 work items
    int n = idx >> 4, c8 = (idx & 15) * 8;
    const size_t gb = (size_t)n * 384 + c8;
    half8 grv = *(const half8*)(g + gb);
    half8 gzv = *(const half8*)(g + gb + 128);
    half8 giv = *(const half8*)(g + gb + 256);
    half8 ghn = *(const half8*)(gn + (size_t)n * 128 + c8);
    half8 hv  = *(const half8*)(h + (size_t)n * 128 + c8);
    half8 outv;
#pragma unroll
    for (int j = 0; j < 8; ++j) {
        int c = c8 + j;
        float r  = sigm((float)grv[j] + bih[c] + bhh[c]);
        float z  = sigm((float)gzv[j] + bih[128 + c] + bhh[128 + c]);
        float nn = tanhf((float)giv[j] + bih[256 + c] + r * ((float)ghn[j] + bhh[256 + c]));
        float hn = (1.0f - z) * nn + z * (float)hv[j];
        outv[j] = (_Float16)(relu_out ? fmaxf(hn, 0.0f) : hn);
    }
    *(half8*)(h + (size_t)n * 128 + c8) = outv;
}

// ---------------- edge gather + scatter-add (fp16 t, fp32 atomics) ----------------
__global__ __launch_bounds__(256) void edge_scatter(const _Float16* __restrict__ t,
    const int* __restrict__ src, const int* __restrict__ dst,
    const float* __restrict__ ew, float* __restrict__ agg)
{
    int e = blockIdx.x * 4 + (threadIdx.x >> 6);
    int lane = threadIdx.x & 63;
    int s = src[e], d = dst[e];
    float w = ew[e];
    half2v tv = *(const half2v*)(t + (size_t)s * 128 + lane * 2);
    atomicAdd(agg + (size_t)d * 128 + lane * 2,     (float)tv[0] * w);
    atomicAdd(agg + (size_t)d * 128 + lane * 2 + 1, (float)tv[1] * w);
}

// ---------------- segment sums (flush on id change; seg ids sorted) ----------------
__global__ __launch_bounds__(256) void seg_sum(const _Float16* __restrict__ x,
    const int* __restrict__ seg, float* __restrict__ sums, float* __restrict__ counts)
{
    int cg = threadIdx.x & 31, rs = threadIdx.x >> 5;
    int r0 = blockIdx.x * 256 + rs * 32;
    float a0 = 0, a1 = 0, a2 = 0, a3 = 0, cnt = 0;
    int cur = seg[r0];
    for (int i = 0; i < 32; ++i) {
        int n = r0 + i;
        int p = seg[n];
        if (p != cur) {
            atomicAdd(&sums[(size_t)cur * 128 + cg * 4 + 0], a0);
            atomicAdd(&sums[(size_t)cur * 128 + cg * 4 + 1], a1);
            atomicAdd(&sums[(size_t)cur * 128 + cg * 4 + 2], a2);
            atomicAdd(&sums[(size_t)cur * 128 + cg * 4 + 3], a3);
            if (cg == 0) atomicAdd(&counts[cur], cnt);
            a0 = a1 = a2 = a3 = 0; cnt = 0; cur = p;
        }
        half4v v = *(const half4v*)(x + (size_t)n * 128 + cg * 4);
        a0 += (float)v[0]; a1 += (float)v[1]; a2 += (float)v[2]; a3 += (float)v[3];
        cnt += 1.0f;
    }
    atomicAdd(&sums[(size_t)cur * 128 + cg * 4 + 0], a0);
    atomicAdd(&sums[(size_t)cur * 128 + cg * 4 + 1], a1);
    atomicAdd(&sums[(size_t)cur * 128 + cg * 4 + 2], a2);
    atomicAdd(&sums[(size_t)cur * 128 + cg * 4 + 3], a3);
    if (cg == 0) atomicAdd(&counts[cur], cnt);
}

// ---------------- gproj[p] = gmean[p] @ W_l[128:256,:] + b_l (fp32) ----------------
__global__ __launch_bounds__(256) void gproj_kernel(const float* __restrict__ sums,
    const float* __restrict__ counts, const float* __restrict__ Wl,
    const float* __restrict__ bl, float* __restrict__ gproj)
{
    __shared__ float gm[128];
    int p = blockIdx.x, m = threadIdx.x;
    if (m < 128) gm[m] = sums[(size_t)p * 128 + m] / fmaxf(counts[p], 1.0f);
    __syncthreads();
    float acc = bl[m];
#pragma unroll 8
    for (int k = 0; k < 128; ++k)
        acc = fmaf(gm[k], Wl[(size_t)(128 + k) * 256 + m], acc);
    gproj[(size_t)p * 256 + m] = acc;
}

// ---------------- final: out[n] = u2[n] . W_l3 + b_l3 ----------------
__global__ __launch_bounds__(256) void final_dot(const _Float16* __restrict__ u2,
    const float* __restrict__ wl3, const float* __restrict__ bl3, float* __restrict__ out)
{
    int gid = blockIdx.x * 256 + threadIdx.x;
    int n = gid >> 6, lane = gid & 63;
    half2v v = *(const half2v*)(u2 + (size_t)n * 128 + lane * 2);
    float s = (float)v[0] * wl3[lane * 2] + (float)v[1] * wl3[lane * 2 + 1];
#pragma unroll
    for (int off = 32; off; off >>= 1) s += __shfl_xor(s, off);
    if (lane == 0) out[n] = s + bl3[0];
}

extern "C" void kernel_launch(void* const* d_in, const int* in_sizes, int n_in,
                              void* d_out, int out_size, void* d_ws, size_t ws_size,
                              hipStream_t stream)
{
    (void)in_sizes; (void)n_in; (void)out_size; (void)ws_size;

    const float* G     = (const float*)d_in[0];
    const int*   ei    = (const int*)d_in[1];
    const float* ew    = (const float*)d_in[2];
    const int*   seg   = (const int*)d_in[4];
    const float* Wemb1 = (const float*)d_in[5];  const float* bemb1 = (const float*)d_in[6];
    const float* Wemb2 = (const float*)d_in[7];  const float* bemb2 = (const float*)d_in[8];
    const float* c1W   = (const float*)d_in[9];
    const float* c1Wih = (const float*)d_in[10]; const float* c1Whh = (const float*)d_in[11];
    const float* c1bih = (const float*)d_in[12]; const float* c1bhh = (const float*)d_in[13];
    const float* c2W   = (const float*)d_in[14];
    const float* c2Wih = (const float*)d_in[15]; const float* c2Whh = (const float*)d_in[16];
    const float* c2bih = (const float*)d_in[17]; const float* c2bhh = (const float*)d_in[18];
    const float* Wg1   = (const float*)d_in[19]; const float* bg1   = (const float*)d_in[20];
    const float* Wg2   = (const float*)d_in[21]; const float* bg2   = (const float*)d_in[22];
    const float* Wl    = (const float*)d_in[23]; const float* bl    = (const float*)d_in[24];
    const float* Wl2   = (const float*)d_in[25]; const float* bl2   = (const float*)d_in[26];
    const float* Wl3   = (const float*)d_in[27]; const float* bl3   = (const float*)d_in[28];

    const int* srcp = ei;
    const int* dstp = ei + NEDGES;

    char* ws = (char*)d_ws;
    const size_t NBH  = (size_t)NNODES * 128 * 2;   // 32MB fp16 node buffer
    const size_t G3B  = (size_t)NNODES * 384 * 2;   // 96MB gate buffer
    const size_t AGGB = (size_t)NNODES * 128 * 4;   // 64MB fp32 agg

    _Float16* hA  = (_Float16*)ws;
    _Float16* hB  = (_Float16*)(ws + NBH);
    _Float16* g   = (_Float16*)(ws + 2 * NBH);                 // [N][384]; reused as u1 [N][256]
    float*    agg = (float*)(ws + 2 * NBH + G3B);
    char*     aux = ws + 2 * NBH + G3B + AGGB;
    float* sums   = (float*)aux;                                // 32KB
    float* counts = (float*)(aux + 32768);                      // pad to 1KB
    float* gproj  = (float*)(aux + 33792);                      // 64KB
    _Float16* wt  = (_Float16*)(aux + 33792 + 65536);

    _Float16* wt_emb2 = wt;                    // [128][128]
    _Float16* wt_c1a  = wt + 16384;
    _Float16* wt_c1b  = wt + 2 * 16384;
    _Float16* wt_c2a  = wt + 3 * 16384;
    _Float16* wt_c2b  = wt + 4 * 16384;
    _Float16* wt_g1   = wt + 5 * 16384;
    _Float16* wt_g2   = wt + 6 * 16384;
    _Float16* wt_l    = wt + 7 * 16384;        // [256][128]
    _Float16* wt_l2   = wt + 7 * 16384 + 32768;        // [128][256]
    _Float16* wt_ih1  = wt + 7 * 16384 + 2 * 32768;    // [384][128]
    _Float16* wt_hh1  = wt_ih1 + 49152;
    _Float16* wt_ih2  = wt_ih1 + 2 * 49152;
    _Float16* wt_hh2  = wt_ih1 + 3 * 49152;

    // ---- weight prep ----
    tr_cvt<<<64, 256, 0, stream>>>(Wemb2, wt_emb2, 128, 128, 128);
    tr_cvt<<<64, 256, 0, stream>>>(c1W,           wt_c1a, 128, 128, 128);
    tr_cvt<<<64, 256, 0, stream>>>(c1W + 16384,   wt_c1b, 128, 128, 128);
    tr_cvt<<<64, 256, 0, stream>>>(c2W,           wt_c2a, 128, 128, 128);
    tr_cvt<<<64, 256, 0, stream>>>(c2W + 16384,   wt_c2b, 128, 128, 128);
    tr_cvt<<<64, 256, 0, stream>>>(Wg1, wt_g1, 128, 128, 128);
    tr_cvt<<<64, 256, 0, stream>>>(Wg2, wt_g2, 128, 128, 128);
    tr_cvt<<<128, 256, 0, stream>>>(Wl,  wt_l,  128, 256, 256);   // top half rows 0..127
    tr_cvt<<<128, 256, 0, stream>>>(Wl2, wt_l2, 256, 128, 128);
    cvt16<<<192, 256, 0, stream>>>(c1Wih, wt_ih1, 49152);
    cvt16<<<192, 256, 0, stream>>>(c1Whh, wt_hh1, 49152);
    cvt16<<<192, 256, 0, stream>>>(c2Wih, wt_ih2, 49152);
    cvt16<<<192, 256, 0, stream>>>(c2Whh, wt_hh2, 49152);

    // ---- embeddings ----
    emb1_kernel<<<NNODES * 128 / 256, 256, 0, stream>>>(G, Wemb1, bemb1, hB);
    gemm_mfma<128, 1, true, 0, true, false><<<512, 256, 0, stream>>>(
        hB, 128, wt_emb2, bemb2, hA, 128, nullptr, nullptr, nullptr);

    // ---- 2 GatedGraphConv layers x 2 GRU iterations ----
    const _Float16* convW[2][2] = { { wt_c1a, wt_c1b }, { wt_c2a, wt_c2b } };
    const _Float16* wih[2] = { wt_ih1, wt_ih2 };
    const _Float16* whh[2] = { wt_hh1, wt_hh2 };
    const float* bihs[2] = { c1bih, c2bih };
    const float* bhhs[2] = { c1bhh, c2bhh };
    for (int cv = 0; cv < 2; ++cv) {
        for (int lyr = 0; lyr < 2; ++lyr) {
            gemm_mfma<128, 1, true, 0, false, false><<<512, 256, 0, stream>>>(
                hA, 128, convW[cv][lyr], nullptr, hB, 128, nullptr, nullptr, nullptr);
            hipMemsetAsync(agg, 0, AGGB, stream);
            edge_scatter<<<NEDGES / 4, 256, 0, stream>>>(hB, srcp, dstp, ew, agg);
            gemm_mfma<128, 3, false, 0, false, false><<<512, 256, 0, stream>>>(
                agg, 128, wih[cv], nullptr, g, 384, nullptr, nullptr, nullptr);
            gemm_mfma<128, 3, true, 1, false, false><<<512, 256, 0, stream>>>(
                hA, 128, whh[cv], nullptr, g, 384, hB, nullptr, nullptr);
            gru_combine<<<NNODES * 16 / 256, 256, 0, stream>>>(
                g, hB, hA, bihs[cv], bhhs[cv], (lyr == 1) ? 1 : 0);
        }
    }

    // ---- head MLP ----
    gemm_mfma<128, 1, true, 0, true, false><<<512, 256, 0, stream>>>(
        hA, 128, wt_g1, bg1, hB, 128, nullptr, nullptr, nullptr);
    gemm_mfma<128, 1, true, 0, false, false><<<512, 256, 0, stream>>>(
        hB, 128, wt_g2, bg2, hA, 128, nullptr, nullptr, nullptr);

    // ---- segment mean -> gproj ----
    hipMemsetAsync(sums, 0, 33792, stream);
    seg_sum<<<NNODES / 256, 256, 0, stream>>>(hA, seg, sums, counts);
    gproj_kernel<<<NPROB, 256, 0, stream>>>(sums, counts, Wl, bl, gproj);

    // ---- u1 = relu(x @ Wl_top + gproj[seg]) [N,256] ----
    gemm_mfma<128, 2, true, 0, true, true><<<512, 256, 0, stream>>>(
        hA, 128, wt_l, nullptr, g, 256, nullptr, gproj, seg);
    // ---- u2 = relu(u1 @ W_l2 + b_l2) [N,128] ----
    gemm_mfma<256, 1, true, 0, true, false><<<256, 256, 0, stream>>>(
        g, 256, wt_l2, bl2, hB, 128, nullptr, nullptr, nullptr);
    // ---- out ----
    final_dot<<<NNODES * 64 / 256, 256, 0, stream>>>(hB, Wl3, bl3, (float*)d_out);
}

// Round 3
// 2100.812 us; speedup vs baseline: 3.1855x; 2.4991x over previous
//
#include <hip/hip_runtime.h>
#include <cstdint>
#include <cstddef>

#define NNODES 131072
#define NEDGES 1048576
#define NPROB  64

typedef _Float16 half8 __attribute__((ext_vector_type(8)));
typedef _Float16 half4v __attribute__((ext_vector_type(4)));
typedef _Float16 half2v __attribute__((ext_vector_type(2)));
typedef float float4v __attribute__((ext_vector_type(4)));

__device__ __forceinline__ float sigm(float x) { return 1.0f / (1.0f + expf(-x)); }

__device__ __forceinline__ void async16(void* lds, const void* g) {
    __builtin_amdgcn_global_load_lds(
        (const __attribute__((address_space(1))) uint32_t*)g,
        (__attribute__((address_space(3))) uint32_t*)lds, 16, 0, 0);
}

// ---------------- weight prep: fp32 -> fp16 (optionally transposed) ----------------
__global__ __launch_bounds__(256) void cvt16(const float* __restrict__ s,
                                             _Float16* __restrict__ d, int n)
{
    int i = blockIdx.x * 256 + threadIdx.x;
    if (i < n) d[i] = (_Float16)s[i];
}

// dst[m*K + k] = src[k*sstride + m]   (dst is [M][K] fp16)
__global__ __launch_bounds__(256) void tr_cvt(const float* __restrict__ src,
    _Float16* __restrict__ dst, int K, int M, int sstride)
{
    int i = blockIdx.x * 256 + threadIdx.x;
    if (i < M * K) {
        int m = i / K, k = i % K;
        dst[i] = (_Float16)src[(size_t)k * sstride + m];
    }
}

// ---------------- CSR build: histogram -> scan -> fill ----------------
__global__ __launch_bounds__(256) void deg_hist(const int* __restrict__ dst,
                                                int* __restrict__ deg)
{
    int e = blockIdx.x * 256 + threadIdx.x;
    atomicAdd(&deg[dst[e]], 1);
}

// block scans 1024 ints (4/thread); exclusive out + block sum
__global__ __launch_bounds__(256) void scan1(const int* __restrict__ deg,
    int* __restrict__ offs, int* __restrict__ bsum)
{
    __shared__ int s[256];
    int b = blockIdx.x, tid = threadIdx.x;
    int4 v = ((const int4*)deg)[b * 256 + tid];
    int t0 = v.x, t1 = t0 + v.y, t2 = t1 + v.z, t3 = t2 + v.w;
    s[tid] = t3;
    __syncthreads();
    for (int off = 1; off < 256; off <<= 1) {
        int x = (tid >= off) ? s[tid - off] : 0;
        __syncthreads();
        if (tid >= off) s[tid] += x;
        __syncthreads();
    }
    int excl = tid ? s[tid - 1] : 0;
    int4 o; o.x = excl; o.y = excl + t0; o.z = excl + t1; o.w = excl + t2;
    ((int4*)offs)[b * 256 + tid] = o;
    if (tid == 255) bsum[b] = s[255];
}

__global__ __launch_bounds__(128) void scan2(int* __restrict__ bsum)
{
    __shared__ int s[128];
    int tid = threadIdx.x;
    s[tid] = bsum[tid];
    __syncthreads();
    for (int off = 1; off < 128; off <<= 1) {
        int x = (tid >= off) ? s[tid - off] : 0;
        __syncthreads();
        if (tid >= off) s[tid] += x;
        __syncthreads();
    }
    bsum[tid] = tid ? s[tid - 1] : 0;
}

__global__ __launch_bounds__(256) void scan3(int* __restrict__ offs,
    const int* __restrict__ bsum, int* __restrict__ pos)
{
    int i = blockIdx.x * 256 + threadIdx.x;
    int v = offs[i] + bsum[i >> 10];
    offs[i] = v;
    pos[i] = v;
    if (i == 0) offs[NNODES] = NEDGES;
}

__global__ __launch_bounds__(256) void csr_fill(const int* __restrict__ src,
    const int* __restrict__ dst, const float* __restrict__ ew,
    int* __restrict__ pos, int2* __restrict__ csr)
{
    int e = blockIdx.x * 256 + threadIdx.x;
    int slot = atomicAdd(&pos[dst[e]], 1);
    csr[slot] = make_int2(src[e], __float_as_int(ew[e]));
}

// ---------------- gather aggregate: agg[n] = sum_{e: dst=n} t[src_e] * w_e ------
__global__ __launch_bounds__(256) void gather_agg(const _Float16* __restrict__ t,
    const int2* __restrict__ csr, const int* __restrict__ offs,
    _Float16* __restrict__ agg)
{
    int node = blockIdx.x * 4 + (threadIdx.x >> 6);
    int lane = threadIdx.x & 63;
    int i = offs[node], end = offs[node + 1];
    float a0 = 0.0f, a1 = 0.0f;
    int2 p;
    if (i < end) p = csr[i];
    while (i < end) {
        int2 cur = p;
        if (i + 1 < end) p = csr[i + 1];
        float w = __int_as_float(cur.y);
        half2v v = *(const half2v*)(t + (size_t)cur.x * 128 + lane * 2);
        a0 = fmaf((float)v[0], w, a0);
        a1 = fmaf((float)v[1], w, a1);
        ++i;
    }
    half2v o; o[0] = (_Float16)a0; o[1] = (_Float16)a1;
    *(half2v*)(agg + (size_t)node * 128 + lane * 2) = o;
}

// ---------------- emb1: x = relu(G @ W1 + b1) -> fp16 ----------------
__global__ __launch_bounds__(256) void emb1_kernel(const float* __restrict__ G,
    const float* __restrict__ W1, const float* __restrict__ b1, _Float16* __restrict__ Y)
{
    int idx = blockIdx.x * 256 + threadIdx.x;
    int n = idx >> 7, c = idx & 127;
    const float* g = G + (size_t)n * 8;
    float y = b1[c];
#pragma unroll
    for (int k = 0; k < 8; ++k) y = fmaf(g[k], W1[k * 128 + c], y);
    Y[(size_t)n * 128 + c] = (_Float16)fmaxf(y, 0.0f);
}

// ---------------- MFMA GEMM: out = act(X @ WtT + bias [+gproj]) ----------------
// Wt is [M][K] fp16 (pre-transposed). X tile: 128 nodes. 4 waves, wave w owns rows
// [w*32, w*32+32). W frags held in registers (hoisted per m-chunk). LDS XOR-swizzled.
// OM: 0 = plain write (out1, stride ostride); 1 = GH mode (mc<2: accumulate into
// out1 [N][384]; mc==2: plain write to out2 [N][128]).
template<int K, int MCH, bool INF16, int OM, bool RELU, bool SEGADD>
__global__ __launch_bounds__(256, 2) void gemm_mfma(
    const void* __restrict__ Xin, int xstride,
    const _Float16* __restrict__ Wt,
    const float* __restrict__ bias,
    _Float16* __restrict__ out1, int ostride,
    _Float16* __restrict__ out2,
    const float* __restrict__ gproj, const int* __restrict__ seg)
{
    constexpr int ROWB = 2 * K;     // LDS row bytes
    constexpr int SPR  = K / 8;     // 16B slots per row
    __shared__ __align__(16) char Xs[128 * ROWB];
    __shared__ __align__(16) char Ws[128 * ROWB];
    const int tid = threadIdx.x, wid = tid >> 6, l = tid & 63;
    const int lr = l & 15, lk = l >> 4;
    const int wrow = wid * 32;

    for (int mc = 0; mc < MCH; ++mc) {
        __syncthreads();   // all waves done with previous Ws/Xs
        {   // stage W chunk [128][K] (swizzled via pre-permuted source)
            const _Float16* wsrc = Wt + (size_t)mc * 128 * K;
            for (int s0 = wid * 64; s0 < 128 * SPR; s0 += 256) {
                int s = s0 + l;
                int row = s / SPR, sub = s % SPR;
                int ksub = sub ^ (row & 7);
                async16(Ws + s0 * 16, (const char*)(wsrc + (size_t)row * K) + ksub * 16);
            }
        }
        asm volatile("s_waitcnt vmcnt(0)" ::: "memory");
        __syncthreads();

        half8 bfr[32];
        if constexpr (K == 128) {
#pragma unroll
            for (int ct = 0; ct < 8; ++ct)
#pragma unroll
                for (int ks = 0; ks < 4; ++ks) {
                    int row = ct * 16 + lr;
                    bfr[ct * 4 + ks] = *(const half8*)(Ws + row * ROWB +
                        ((ks * 64 + lk * 16) ^ ((row & 7) << 4)));
                }
        }

        for (int t = blockIdx.x; t < NNODES / 128; t += gridDim.x) {
            const int nbase = t * 128;
            __syncthreads();   // previous tile's reads complete before overwrite
            if constexpr (INF16) {
                const _Float16* xsrc = (const _Float16*)Xin;
                for (int s0 = wid * 64; s0 < 128 * SPR; s0 += 256) {
                    int s = s0 + l;
                    int row = s / SPR, sub = s % SPR;
                    int ksub = sub ^ (row & 7);
                    async16(Xs + s0 * 16,
                            (const char*)(xsrc + (size_t)(nbase + row) * xstride) + ksub * 16);
                }
                asm volatile("s_waitcnt vmcnt(0)" ::: "memory");
            } else {
                const float* xsrc = (const float*)Xin;
                for (int s = tid; s < 128 * SPR; s += 256) {
                    int row = s / SPR, sub = s % SPR;
                    int ksub = sub ^ (row & 7);
                    const float* p = xsrc + (size_t)(nbase + row) * xstride + ksub * 8;
                    float4 u = ((const float4*)p)[0];
                    float4 v = ((const float4*)p)[1];
                    half8 hv;
                    hv[0] = (_Float16)u.x; hv[1] = (_Float16)u.y;
                    hv[2] = (_Float16)u.z; hv[3] = (_Float16)u.w;
                    hv[4] = (_Float16)v.x; hv[5] = (_Float16)v.y;
                    hv[6] = (_Float16)v.z; hv[7] = (_Float16)v.w;
                    *(half8*)(Xs + s * 16) = hv;
                }
            }
            __syncthreads();

            float4v acc[2][8];
#pragma unroll
            for (int i = 0; i < 2; ++i)
#pragma unroll
                for (int j = 0; j < 8; ++j)
#pragma unroll
                    for (int q = 0; q < 4; ++q) acc[i][j][q] = 0.0f;

            if constexpr (K == 128) {
#pragma unroll
                for (int rt = 0; rt < 2; ++rt) {
                    half8 a[4];
                    int row = wrow + rt * 16 + lr;
#pragma unroll
                    for (int ks = 0; ks < 4; ++ks)
                        a[ks] = *(const half8*)(Xs + row * ROWB +
                            ((ks * 64 + lk * 16) ^ ((row & 7) << 4)));
#pragma unroll
                    for (int ct = 0; ct < 8; ++ct)
#pragma unroll
                        for (int ks = 0; ks < 4; ++ks)
                            acc[rt][ct] = __builtin_amdgcn_mfma_f32_16x16x32_f16(
                                a[ks], bfr[ct * 4 + ks], acc[rt][ct], 0, 0, 0);
                }
            } else {   // K == 256: frags reloaded per k-half
#pragma unroll
                for (int kc = 0; kc < 2; ++kc) {
#pragma unroll
                    for (int ct = 0; ct < 8; ++ct)
#pragma unroll
                        for (int ks = 0; ks < 4; ++ks) {
                            int row = ct * 16 + lr;
                            bfr[ct * 4 + ks] = *(const half8*)(Ws + row * ROWB +
                                (((kc * 4 + ks) * 64 + lk * 16) ^ ((row & 7) << 4)));
                        }
#pragma unroll
                    for (int rt = 0; rt < 2; ++rt) {
                        half8 a[4];
                        int row = wrow + rt * 16 + lr;
#pragma unroll
                        for (int ks = 0; ks < 4; ++ks)
                            a[ks] = *(const half8*)(Xs + row * ROWB +
                                (((kc * 4 + ks) * 64 + lk * 16) ^ ((row & 7) << 4)));
#pragma unroll
                        for (int ct = 0; ct < 8; ++ct)
#pragma unroll
                            for (int ks = 0; ks < 4; ++ks)
                                acc[rt][ct] = __builtin_amdgcn_mfma_f32_16x16x32_f16(
                                    a[ks], bfr[ct * 4 + ks], acc[rt][ct], 0, 0, 0);
                    }
                }
            }

            // epilogue: C/D layout col = lane&15, row = (lane>>4)*4 + j
#pragma unroll
            for (int rt = 0; rt < 2; ++rt)
#pragma unroll
            for (int ct = 0; ct < 8; ++ct) {
                const int col = ct * 16 + lr;
                float bv = 0.0f;
                if (bias) bv = bias[mc * 128 + col];
#pragma unroll
                for (int j = 0; j < 4; ++j) {
                    const int n = nbase + wrow + rt * 16 + lk * 4 + j;
                    float v = acc[rt][ct][j] + bv;
                    if constexpr (SEGADD)
                        v += gproj[(size_t)seg[n] * 256 + mc * 128 + col];
                    if constexpr (OM == 1) {
                        if (mc < 2) {
                            size_t o = (size_t)n * ostride + mc * 128 + col;
                            out1[o] = (_Float16)(v + (float)out1[o]);
                        } else {
                            out2[(size_t)n * 128 + col] = (_Float16)v;
                        }
                    } else {
                        if constexpr (RELU) v = fmaxf(v, 0.0f);
                        out1[(size_t)n * ostride + mc * 128 + col] = (_Float16)v;
                    }
                }
            }
        }
    }
}

// ---------------- GRU combine: h' = (1-z)*tanh(in+r*hn) + z*h ----------------
__global__ __launch_bounds__(256) void gru_combine(const _Float16* __restrict__ g,
    const _Float16* __restrict__ gn, _Float16* __restrict__ h,
    const float* __restrict__ bih, const float* __restrict__ bhh, int relu_out)
{
    int idx = blockIdx.x * 256 + threadIdx.x;   // N*16 work items
    int n = idx >> 4, c8 = (idx & 15) * 8;
    const size_t gb = (size_t)n * 384 + c8;
    half8 grv = *(const half8*)(g + gb);
    half8 gzv = *(const half8*)(g + gb + 128);
    half8 giv = *(const half8*)(g + gb + 256);
    half8 ghn = *(const half8*)(gn + (size_t)n * 128 + c8);
    half8 hv  = *(const half8*)(h + (size_t)n * 128 + c8);
    half8 outv;
#pragma unroll
    for (int j = 0; j < 8; ++j) {
        int c = c8 + j;
        float r  = sigm((float)grv[j] + bih[c] + bhh[c]);
        float z  = sigm((float)gzv[j] + bih[128 + c] + bhh[128 + c]);
        float nn = tanhf((float)giv[j] + bih[256 + c] + r * ((float)ghn[j] + bhh[256 + c]));
        float hn = (1.0f - z) * nn + z * (float)hv[j];
        outv[j] = (_Float16)(relu_out ? fmaxf(hn, 0.0f) : hn);
    }
    *(half8*)(h + (size_t)n * 128 + c8) = outv;
}

// ---------------- segment sums (flush on id change; seg ids sorted) ----------------
__global__ __launch_bounds__(256) void seg_sum(const _Float16* __restrict__ x,
    const int* __restrict__ seg, float* __restrict__ sums, float* __restrict__ counts)
{
    int cg = threadIdx.x & 31, rs = threadIdx.x >> 5;
    int r0 = blockIdx.x * 256 + rs * 32;
    float a0 = 0, a1 = 0, a2 = 0, a3 = 0, cnt = 0;
    int cur = seg[r0];
    for (int i = 0; i < 32; ++i) {
        int n = r0 + i;
        int p = seg[n];
        if (p != cur) {
            atomicAdd(&sums[(size_t)cur * 128 + cg * 4 + 0], a0);
            atomicAdd(&sums[(size_t)cur * 128 + cg * 4 + 1], a1);
            atomicAdd(&sums[(size_t)cur * 128 + cg * 4 + 2], a2);
            atomicAdd(&sums[(size_t)cur * 128 + cg * 4 + 3], a3);
            if (cg == 0) atomicAdd(&counts[cur], cnt);
            a0 = a1 = a2 = a3 = 0; cnt = 0; cur = p;
        }
        half4v v = *(const half4v*)(x + (size_t)n * 128 + cg * 4);
        a0 += (float)v[0]; a1 += (float)v[1]; a2 += (float)v[2]; a3 += (float)v[3];
        cnt += 1.0f;
    }
    atomicAdd(&sums[(size_t)cur * 128 + cg * 4 + 0], a0);
    atomicAdd(&sums[(size_t)cur * 128 + cg * 4 + 1], a1);
    atomicAdd(&sums[(size_t)cur * 128 + cg * 4 + 2], a2);
    atomicAdd(&sums[(size_t)cur * 128 + cg * 4 + 3], a3);
    if (cg == 0) atomicAdd(&counts[cur], cnt);
}

// ---------------- gproj[p] = gmean[p] @ W_l[128:256,:] + b_l (fp32) ----------------
__global__ __launch_bounds__(256) void gproj_kernel(const float* __restrict__ sums,
    const float* __restrict__ counts, const float* __restrict__ Wl,
    const float* __restrict__ bl, float* __restrict__ gproj)
{
    __shared__ float gm[128];
    int p = blockIdx.x, m = threadIdx.x;
    if (m < 128) gm[m] = sums[(size_t)p * 128 + m] / fmaxf(counts[p], 1.0f);
    __syncthreads();
    float acc = bl[m];
#pragma unroll 8
    for (int k = 0; k < 128; ++k)
        acc = fmaf(gm[k], Wl[(size_t)(128 + k) * 256 + m], acc);
    gproj[(size_t)p * 256 + m] = acc;
}

// ---------------- final: out[n] = u2[n] . W_l3 + b_l3 ----------------
__global__ __launch_bounds__(256) void final_dot(const _Float16* __restrict__ u2,
    const float* __restrict__ wl3, const float* __restrict__ bl3, float* __restrict__ out)
{
    int gid = blockIdx.x * 256 + threadIdx.x;
    int n = gid >> 6, lane = gid & 63;
    half2v v = *(const half2v*)(u2 + (size_t)n * 128 + lane * 2);
    float s = (float)v[0] * wl3[lane * 2] + (float)v[1] * wl3[lane * 2 + 1];
#pragma unroll
    for (int off = 32; off; off >>= 1) s += __shfl_xor(s, off);
    if (lane == 0) out[n] = s + bl3[0];
}

extern "C" void kernel_launch(void* const* d_in, const int* in_sizes, int n_in,
                              void* d_out, int out_size, void* d_ws, size_t ws_size,
                              hipStream_t stream)
{
    (void)in_sizes; (void)n_in; (void)out_size; (void)ws_size;

    const float* G     = (const float*)d_in[0];
    const int*   ei    = (const int*)d_in[1];
    const float* ew    = (const float*)d_in[2];
    const int*   seg   = (const int*)d_in[4];
    const float* Wemb1 = (const float*)d_in[5];  const float* bemb1 = (const float*)d_in[6];
    const float* Wemb2 = (const float*)d_in[7];  const float* bemb2 = (const float*)d_in[8];
    const float* c1W   = (const float*)d_in[9];
    const float* c1Wih = (const float*)d_in[10]; const float* c1Whh = (const float*)d_in[11];
    const float* c1bih = (const float*)d_in[12]; const float* c1bhh = (const float*)d_in[13];
    const float* c2W   = (const float*)d_in[14];
    const float* c2Wih = (const float*)d_in[15]; const float* c2Whh = (const float*)d_in[16];
    const float* c2bih = (const float*)d_in[17]; const float* c2bhh = (const float*)d_in[18];
    const float* Wg1   = (const float*)d_in[19]; const float* bg1   = (const float*)d_in[20];
    const float* Wg2   = (const float*)d_in[21]; const float* bg2   = (const float*)d_in[22];
    const float* Wl    = (const float*)d_in[23]; const float* bl    = (const float*)d_in[24];
    const float* Wl2   = (const float*)d_in[25]; const float* bl2   = (const float*)d_in[26];
    const float* Wl3   = (const float*)d_in[27]; const float* bl3   = (const float*)d_in[28];

    const int* srcp = ei;
    const int* dstp = ei + NEDGES;

    char* ws = (char*)d_ws;
    const size_t NBH  = (size_t)NNODES * 128 * 2;   // 32MB fp16 node buffer
    const size_t G3B  = (size_t)NNODES * 384 * 2;   // 96MB gate buffer

    _Float16* hA   = (_Float16*)ws;
    _Float16* hB   = (_Float16*)(ws + NBH);
    _Float16* g    = (_Float16*)(ws + 2 * NBH);                // [N][384]; reused as u1 [N][256]
    _Float16* aggH = (_Float16*)(ws + 2 * NBH + G3B);          // [N][128] fp16
    char*     aux  = ws + 3 * NBH + G3B;
    float* sums   = (float*)aux;                                // 32KB
    float* counts = (float*)(aux + 32768);                      // 1KB pad
    float* gproj  = (float*)(aux + 33792);                      // 64KB
    // CSR area
    int*  deg   = (int*)(aux + 33792 + 65536);                  // 512KB
    int*  offs  = deg + NNODES;                                 // 512KB + 4 (uses +64 pad)
    int*  pos   = offs + NNODES + 64;                           // 512KB
    int2* csr   = (int2*)(pos + NNODES);                        // 8MB
    _Float16* wt = (_Float16*)((char*)csr + (size_t)NEDGES * 8);

    _Float16* wt_emb2 = wt;                    // [128][128]
    _Float16* wt_c1a  = wt + 16384;
    _Float16* wt_c1b  = wt + 2 * 16384;
    _Float16* wt_c2a  = wt + 3 * 16384;
    _Float16* wt_c2b  = wt + 4 * 16384;
    _Float16* wt_g1   = wt + 5 * 16384;
    _Float16* wt_g2   = wt + 6 * 16384;
    _Float16* wt_l    = wt + 7 * 16384;        // [256][128]
    _Float16* wt_l2   = wt + 7 * 16384 + 32768;        // [128][256]
    _Float16* wt_ih1  = wt + 7 * 16384 + 2 * 32768;    // [384][128]
    _Float16* wt_hh1  = wt_ih1 + 49152;
    _Float16* wt_ih2  = wt_ih1 + 2 * 49152;
    _Float16* wt_hh2  = wt_ih1 + 3 * 49152;

    // ---- weight prep ----
    tr_cvt<<<64, 256, 0, stream>>>(Wemb2, wt_emb2, 128, 128, 128);
    tr_cvt<<<64, 256, 0, stream>>>(c1W,           wt_c1a, 128, 128, 128);
    tr_cvt<<<64, 256, 0, stream>>>(c1W + 16384,   wt_c1b, 128, 128, 128);
    tr_cvt<<<64, 256, 0, stream>>>(c2W,           wt_c2a, 128, 128, 128);
    tr_cvt<<<64, 256, 0, stream>>>(c2W + 16384,   wt_c2b, 128, 128, 128);
    tr_cvt<<<64, 256, 0, stream>>>(Wg1, wt_g1, 128, 128, 128);
    tr_cvt<<<64, 256, 0, stream>>>(Wg2, wt_g2, 128, 128, 128);
    tr_cvt<<<128, 256, 0, stream>>>(Wl,  wt_l,  128, 256, 256);   // top half rows 0..127
    tr_cvt<<<128, 256, 0, stream>>>(Wl2, wt_l2, 256, 128, 128);
    cvt16<<<192, 256, 0, stream>>>(c1Wih, wt_ih1, 49152);
    cvt16<<<192, 256, 0, stream>>>(c1Whh, wt_hh1, 49152);
    cvt16<<<192, 256, 0, stream>>>(c2Wih, wt_ih2, 49152);
    cvt16<<<192, 256, 0, stream>>>(c2Whh, wt_hh2, 49152);

    // ---- CSR build (once; reused by all 4 aggregations) ----
    hipMemsetAsync(deg, 0, NNODES * 4, stream);
    deg_hist<<<NEDGES / 256, 256, 0, stream>>>(dstp, deg);
    scan1<<<128, 256, 0, stream>>>(deg, offs, pos /*bsum scratch*/);
    scan2<<<1, 128, 0, stream>>>(pos);
    scan3<<<NNODES / 256, 256, 0, stream>>>(offs, pos, deg /*pos out*/);
    csr_fill<<<NEDGES / 256, 256, 0, stream>>>(srcp, dstp, ew, deg, csr);

    // ---- embeddings ----
    emb1_kernel<<<NNODES * 128 / 256, 256, 0, stream>>>(G, Wemb1, bemb1, hB);
    gemm_mfma<128, 1, true, 0, true, false><<<512, 256, 0, stream>>>(
        hB, 128, wt_emb2, bemb2, hA, 128, nullptr, nullptr, nullptr);

    // ---- 2 GatedGraphConv layers x 2 GRU iterations ----
    const _Float16* convW[2][2] = { { wt_c1a, wt_c1b }, { wt_c2a, wt_c2b } };
    const _Float16* wih[2] = { wt_ih1, wt_ih2 };
    const _Float16* whh[2] = { wt_hh1, wt_hh2 };
    const float* bihs[2] = { c1bih, c2bih };
    const float* bhhs[2] = { c1bhh, c2bhh };
    for (int cv = 0; cv < 2; ++cv) {
        for (int lyr = 0; lyr < 2; ++lyr) {
            gemm_mfma<128, 1, true, 0, false, false><<<512, 256, 0, stream>>>(
                hA, 128, convW[cv][lyr], nullptr, hB, 128, nullptr, nullptr, nullptr);
            gather_agg<<<NNODES / 4, 256, 0, stream>>>(hB, csr, offs, aggH);
            gemm_mfma<128, 3, true, 0, false, false><<<512, 256, 0, stream>>>(
                aggH, 128, wih[cv], nullptr, g, 384, nullptr, nullptr, nullptr);
            gemm_mfma<128, 3, true, 1, false, false><<<512, 256, 0, stream>>>(
                hA, 128, whh[cv], nullptr, g, 384, hB, nullptr, nullptr);
            gru_combine<<<NNODES * 16 / 256, 256, 0, stream>>>(
                g, hB, hA, bihs[cv], bhhs[cv], (lyr == 1) ? 1 : 0);
        }
    }

    // ---- head MLP ----
    gemm_mfma<128, 1, true, 0, true, false><<<512, 256, 0, stream>>>(
        hA, 128, wt_g1, bg1, hB, 128, nullptr, nullptr, nullptr);
    gemm_mfma<128, 1, true, 0, false, false><<<512, 256, 0, stream>>>(
        hB, 128, wt_g2, bg2, hA, 128, nullptr, nullptr, nullptr);

    // ---- segment mean -> gproj ----
    hipMemsetAsync(sums, 0, 33792, stream);
    seg_sum<<<NNODES / 256, 256, 0, stream>>>(hA, seg, sums, counts);
    gproj_kernel<<<NPROB, 256, 0, stream>>>(sums, counts, Wl, bl, gproj);

    // ---- u1 = relu(x @ Wl_top + gproj[seg]) [N,256] ----
    gemm_mfma<128, 2, true, 0, true, true><<<512, 256, 0, stream>>>(
        hA, 128, wt_l, nullptr, g, 256, nullptr, gproj, seg);
    // ---- u2 = relu(u1 @ W_l2 + b_l2) [N,128] ----
    gemm_mfma<256, 1, true, 0, true, false><<<256, 256, 0, stream>>>(
        g, 256, wt_l2, bl2, hB, 128, nullptr, nullptr, nullptr);
    // ---- out ----
    final_dot<<<NNODES * 64 / 256, 256, 0, stream>>>(hB, Wl3, bl3, (float*)d_out);
}

// Round 4
// 1862.568 us; speedup vs baseline: 3.5930x; 1.1279x over previous
//
#include <hip/hip_runtime.h>
#include <cstdint>
#include <cstddef>

#define NNODES 131072
#define NEDGES 1048576
#define NPROB  64

typedef _Float16 half8 __attribute__((ext_vector_type(8)));
typedef _Float16 half4v __attribute__((ext_vector_type(4)));
typedef _Float16 half2v __attribute__((ext_vector_type(2)));
typedef float float4v __attribute__((ext_vector_type(4)));

__device__ __forceinline__ float fsigm(float x) {
    return __builtin_amdgcn_rcpf(1.0f + __expf(-x));
}
__device__ __forceinline__ float ftanh(float x) {
    // 1 - 2/(e^{2x}+1); exp->inf => 1, exp->0 => -1
    return 1.0f - 2.0f * __builtin_amdgcn_rcpf(__expf(2.0f * x) + 1.0f);
}

__device__ __forceinline__ void async16(void* lds, const void* g) {
    __builtin_amdgcn_global_load_lds(
        (const __attribute__((address_space(1))) uint32_t*)g,
        (__attribute__((address_space(3))) uint32_t*)lds, 16, 0, 0);
}

// ---------------- weight prep: fp32 -> fp16 (optionally transposed) ----------------
__global__ __launch_bounds__(256) void cvt16(const float* __restrict__ s,
                                             _Float16* __restrict__ d, int n)
{
    int i = blockIdx.x * 256 + threadIdx.x;
    if (i < n) d[i] = (_Float16)s[i];
}

// dst[m*K + k] = src[k*sstride + m]   (dst is [M][K] fp16)
__global__ __launch_bounds__(256) void tr_cvt(const float* __restrict__ src,
    _Float16* __restrict__ dst, int K, int M, int sstride)
{
    int i = blockIdx.x * 256 + threadIdx.x;
    if (i < M * K) {
        int m = i / K, k = i % K;
        dst[i] = (_Float16)src[(size_t)k * sstride + m];
    }
}

// ---------------- CSR build: histogram -> scan -> fill ----------------
__global__ __launch_bounds__(256) void deg_hist(const int* __restrict__ dst,
                                                int* __restrict__ deg)
{
    int e = blockIdx.x * 256 + threadIdx.x;
    atomicAdd(&deg[dst[e]], 1);
}

__global__ __launch_bounds__(256) void scan1(const int* __restrict__ deg,
    int* __restrict__ offs, int* __restrict__ bsum)
{
    __shared__ int s[256];
    int b = blockIdx.x, tid = threadIdx.x;
    int4 v = ((const int4*)deg)[b * 256 + tid];
    int t0 = v.x, t1 = t0 + v.y, t2 = t1 + v.z, t3 = t2 + v.w;
    s[tid] = t3;
    __syncthreads();
    for (int off = 1; off < 256; off <<= 1) {
        int x = (tid >= off) ? s[tid - off] : 0;
        __syncthreads();
        if (tid >= off) s[tid] += x;
        __syncthreads();
    }
    int excl = tid ? s[tid - 1] : 0;
    int4 o; o.x = excl; o.y = excl + t0; o.z = excl + t1; o.w = excl + t2;
    ((int4*)offs)[b * 256 + tid] = o;
    if (tid == 255) bsum[b] = s[255];
}

__global__ __launch_bounds__(128) void scan2(int* __restrict__ bsum)
{
    __shared__ int s[128];
    int tid = threadIdx.x;
    s[tid] = bsum[tid];
    __syncthreads();
    for (int off = 1; off < 128; off <<= 1) {
        int x = (tid >= off) ? s[tid - off] : 0;
        __syncthreads();
        if (tid >= off) s[tid] += x;
        __syncthreads();
    }
    bsum[tid] = tid ? s[tid - 1] : 0;
}

__global__ __launch_bounds__(256) void scan3(int* __restrict__ offs,
    const int* __restrict__ bsum, int* __restrict__ pos)
{
    int i = blockIdx.x * 256 + threadIdx.x;
    int v = offs[i] + bsum[i >> 10];
    offs[i] = v;
    pos[i] = v;
    if (i == 0) offs[NNODES] = NEDGES;
}

__global__ __launch_bounds__(256) void csr_fill(const int* __restrict__ src,
    const int* __restrict__ dst, const float* __restrict__ ew,
    int* __restrict__ pos, int2* __restrict__ csr)
{
    int e = blockIdx.x * 256 + threadIdx.x;
    int slot = atomicAdd(&pos[dst[e]], 1);
    csr[slot] = make_int2(src[e], __float_as_int(ew[e]));
}

// ---------------- gather aggregate: agg[n] = sum_{e: dst=n} t[src_e] * w_e ------
__global__ __launch_bounds__(256) void gather_agg(const _Float16* __restrict__ t,
    const int2* __restrict__ csr, const int* __restrict__ offs,
    _Float16* __restrict__ agg)
{
    int node = blockIdx.x * 4 + (threadIdx.x >> 6);
    int lane = threadIdx.x & 63;
    int i = offs[node], end = offs[node + 1];
    float a0 = 0.0f, a1 = 0.0f;
    int2 p;
    if (i < end) p = csr[i];
    while (i < end) {
        int2 cur = p;
        if (i + 1 < end) p = csr[i + 1];
        float w = __int_as_float(cur.y);
        half2v v = *(const half2v*)(t + (size_t)cur.x * 128 + lane * 2);
        a0 = fmaf((float)v[0], w, a0);
        a1 = fmaf((float)v[1], w, a1);
        ++i;
    }
    half2v o; o[0] = (_Float16)a0; o[1] = (_Float16)a1;
    *(half2v*)(agg + (size_t)node * 128 + lane * 2) = o;
}

// ---------------- emb1: x = relu(G @ W1 + b1) -> fp16 ----------------
__global__ __launch_bounds__(256) void emb1_kernel(const float* __restrict__ G,
    const float* __restrict__ W1, const float* __restrict__ b1, _Float16* __restrict__ Y)
{
    int idx = blockIdx.x * 256 + threadIdx.x;
    int n = idx >> 7, c = idx & 127;
    const float* g = G + (size_t)n * 8;
    float y = b1[c];
#pragma unroll
    for (int k = 0; k < 8; ++k) y = fmaf(g[k], W1[k * 128 + c], y);
    Y[(size_t)n * 128 + c] = (_Float16)fmaxf(y, 0.0f);
}

// ---------------- MFMA GEMM: out = act(X @ WtT + bias [+gproj]) ----------------
// Wt is [M][K] fp16 (pre-transposed). 128-node tiles, 4 waves. W frags hoisted
// into registers (K=128). LDS XOR-swizzled, staged via global_load_lds.
template<int K, int MCH, bool INF16, bool RELU, bool SEGADD>
__global__ __launch_bounds__(256, 2) void gemm_mfma(
    const void* __restrict__ Xin, int xstride,
    const _Float16* __restrict__ Wt,
    const float* __restrict__ bias,
    _Float16* __restrict__ out1, int ostride,
    const float* __restrict__ gproj, const int* __restrict__ seg)
{
    constexpr int ROWB = 2 * K;     // LDS row bytes
    constexpr int SPR  = K / 8;     // 16B slots per row
    __shared__ __align__(16) char Xs[128 * ROWB];
    __shared__ __align__(16) char Ws[128 * ROWB];
    const int tid = threadIdx.x, wid = tid >> 6, l = tid & 63;
    const int lr = l & 15, lk = l >> 4;
    const int wrow = wid * 32;

    for (int mc = 0; mc < MCH; ++mc) {
        __syncthreads();
        {   // stage W chunk [128][K]
            const _Float16* wsrc = Wt + (size_t)mc * 128 * K;
            for (int s0 = wid * 64; s0 < 128 * SPR; s0 += 256) {
                int s = s0 + l;
                int row = s / SPR, sub = s % SPR;
                int ksub = sub ^ (row & 7);
                async16(Ws + s0 * 16, (const char*)(wsrc + (size_t)row * K) + ksub * 16);
            }
        }
        asm volatile("s_waitcnt vmcnt(0)" ::: "memory");
        __syncthreads();

        half8 bfr[32];
        if constexpr (K == 128) {
#pragma unroll
            for (int ct = 0; ct < 8; ++ct)
#pragma unroll
                for (int ks = 0; ks < 4; ++ks) {
                    int row = ct * 16 + lr;
                    bfr[ct * 4 + ks] = *(const half8*)(Ws + row * ROWB +
                        ((ks * 64 + lk * 16) ^ ((row & 7) << 4)));
                }
        }

        for (int t = blockIdx.x; t < NNODES / 128; t += gridDim.x) {
            const int nbase = t * 128;
            __syncthreads();
            if constexpr (INF16) {
                const _Float16* xsrc = (const _Float16*)Xin;
                for (int s0 = wid * 64; s0 < 128 * SPR; s0 += 256) {
                    int s = s0 + l;
                    int row = s / SPR, sub = s % SPR;
                    int ksub = sub ^ (row & 7);
                    async16(Xs + s0 * 16,
                            (const char*)(xsrc + (size_t)(nbase + row) * xstride) + ksub * 16);
                }
                asm volatile("s_waitcnt vmcnt(0)" ::: "memory");
            } else {
                const float* xsrc = (const float*)Xin;
                for (int s = tid; s < 128 * SPR; s += 256) {
                    int row = s / SPR, sub = s % SPR;
                    int ksub = sub ^ (row & 7);
                    const float* p = xsrc + (size_t)(nbase + row) * xstride + ksub * 8;
                    float4 u = ((const float4*)p)[0];
                    float4 v = ((const float4*)p)[1];
                    half8 hv;
                    hv[0] = (_Float16)u.x; hv[1] = (_Float16)u.y;
                    hv[2] = (_Float16)u.z; hv[3] = (_Float16)u.w;
                    hv[4] = (_Float16)v.x; hv[5] = (_Float16)v.y;
                    hv[6] = (_Float16)v.z; hv[7] = (_Float16)v.w;
                    *(half8*)(Xs + s * 16) = hv;
                }
            }
            __syncthreads();

            float4v acc[2][8];
#pragma unroll
            for (int i = 0; i < 2; ++i)
#pragma unroll
                for (int j = 0; j < 8; ++j)
#pragma unroll
                    for (int q = 0; q < 4; ++q) acc[i][j][q] = 0.0f;

            if constexpr (K == 128) {
#pragma unroll
                for (int rt = 0; rt < 2; ++rt) {
                    half8 a[4];
                    int row = wrow + rt * 16 + lr;
#pragma unroll
                    for (int ks = 0; ks < 4; ++ks)
                        a[ks] = *(const half8*)(Xs + row * ROWB +
                            ((ks * 64 + lk * 16) ^ ((row & 7) << 4)));
#pragma unroll
                    for (int ct = 0; ct < 8; ++ct)
#pragma unroll
                        for (int ks = 0; ks < 4; ++ks)
                            acc[rt][ct] = __builtin_amdgcn_mfma_f32_16x16x32_f16(
                                a[ks], bfr[ct * 4 + ks], acc[rt][ct], 0, 0, 0);
                }
            } else {   // K == 256
#pragma unroll
                for (int kc = 0; kc < 2; ++kc) {
#pragma unroll
                    for (int ct = 0; ct < 8; ++ct)
#pragma unroll
                        for (int ks = 0; ks < 4; ++ks) {
                            int row = ct * 16 + lr;
                            bfr[ct * 4 + ks] = *(const half8*)(Ws + row * ROWB +
                                (((kc * 4 + ks) * 64 + lk * 16) ^ ((row & 7) << 4)));
                        }
#pragma unroll
                    for (int rt = 0; rt < 2; ++rt) {
                        half8 a[4];
                        int row = wrow + rt * 16 + lr;
#pragma unroll
                        for (int ks = 0; ks < 4; ++ks)
                            a[ks] = *(const half8*)(Xs + row * ROWB +
                                (((kc * 4 + ks) * 64 + lk * 16) ^ ((row & 7) << 4)));
#pragma unroll
                        for (int ct = 0; ct < 8; ++ct)
#pragma unroll
                            for (int ks = 0; ks < 4; ++ks)
                                acc[rt][ct] = __builtin_amdgcn_mfma_f32_16x16x32_f16(
                                    a[ks], bfr[ct * 4 + ks], acc[rt][ct], 0, 0, 0);
                    }
                }
            }

#pragma unroll
            for (int rt = 0; rt < 2; ++rt)
#pragma unroll
            for (int ct = 0; ct < 8; ++ct) {
                const int col = ct * 16 + lr;
                float bv = 0.0f;
                if (bias) bv = bias[mc * 128 + col];
#pragma unroll
                for (int j = 0; j < 4; ++j) {
                    const int n = nbase + wrow + rt * 16 + lk * 4 + j;
                    float v = acc[rt][ct][j] + bv;
                    if constexpr (SEGADD)
                        v += gproj[(size_t)seg[n] * 256 + mc * 128 + col];
                    if constexpr (RELU) v = fmaxf(v, 0.0f);
                    out1[(size_t)n * ostride + mc * 128 + col] = (_Float16)v;
                }
            }
        }
    }
}

// ---------------- fused gh-GEMM + GRU combine (in-place h update) ----------------
// gh = h @ WhhT (Wt=[384][128]); per tile compute r,z chunks into registers, then
// n-chunk and h' = (1-z)*n + z*h_old.  gi read from g [N][384].
__global__ __launch_bounds__(256, 2) void gemm_gru(
    _Float16* h,                                   // [N][128] in/out
    const _Float16* __restrict__ Wt,               // Whh fp16 [384][128]
    const _Float16* __restrict__ g,                // gi [N][384]
    const float* __restrict__ bih, const float* __restrict__ bhh,
    int relu_out)
{
    constexpr int ROWB = 256;    // 128 fp16
    constexpr int SPR  = 16;
    __shared__ __align__(16) char Xs[128 * ROWB];
    __shared__ __align__(16) char Ws[128 * ROWB];
    const int tid = threadIdx.x, wid = tid >> 6, l = tid & 63;
    const int lr = l & 15, lk = l >> 4;
    const int wrow = wid * 32;

    for (int t = blockIdx.x; t < NNODES / 128; t += gridDim.x) {
        const int nbase = t * 128;
        __syncthreads();   // previous tile fully consumed (Xs + Ws)
        // stage Xs = h tile (async; completes at mc=0's vmcnt)
        for (int s0 = wid * 64; s0 < 128 * SPR; s0 += 256) {
            int s = s0 + l;
            int row = s / SPR, sub = s % SPR;
            int ksub = sub ^ (row & 7);
            async16(Xs + s0 * 16, (const char*)(h + (size_t)(nbase + row) * 128) + ksub * 16);
        }

        float4v rg[2][8], zg[2][8];
#pragma unroll
        for (int mc = 0; mc < 3; ++mc) {
            if (mc) __syncthreads();   // all waves done reading previous Ws chunk
            {
                const _Float16* wsrc = Wt + (size_t)mc * 128 * 128;
                for (int s0 = wid * 64; s0 < 128 * SPR; s0 += 256) {
                    int s = s0 + l;
                    int row = s / SPR, sub = s % SPR;
                    int ksub = sub ^ (row & 7);
                    async16(Ws + s0 * 16, (const char*)(wsrc + (size_t)row * 128) + ksub * 16);
                }
            }
            asm volatile("s_waitcnt vmcnt(0)" ::: "memory");
            __syncthreads();

            // A-frags for this wave's 32 rows
            half8 a[2][4];
#pragma unroll
            for (int rt = 0; rt < 2; ++rt) {
                int row = wrow + rt * 16 + lr;
#pragma unroll
                for (int ks = 0; ks < 4; ++ks)
                    a[rt][ks] = *(const half8*)(Xs + row * ROWB +
                        ((ks * 64 + lk * 16) ^ ((row & 7) << 4)));
            }

            float4v acc[2][8];
#pragma unroll
            for (int i = 0; i < 2; ++i)
#pragma unroll
                for (int j = 0; j < 8; ++j)
#pragma unroll
                    for (int q = 0; q < 4; ++q) acc[i][j][q] = 0.0f;

#pragma unroll
            for (int ct = 0; ct < 8; ++ct) {
                int row = ct * 16 + lr;
#pragma unroll
                for (int ks = 0; ks < 4; ++ks) {
                    half8 b = *(const half8*)(Ws + row * ROWB +
                        ((ks * 64 + lk * 16) ^ ((row & 7) << 4)));
                    acc[0][ct] = __builtin_amdgcn_mfma_f32_16x16x32_f16(a[0][ks], b, acc[0][ct], 0, 0, 0);
                    acc[1][ct] = __builtin_amdgcn_mfma_f32_16x16x32_f16(a[1][ks], b, acc[1][ct], 0, 0, 0);
                }
            }

            // epilogue
#pragma unroll
            for (int rt = 0; rt < 2; ++rt)
#pragma unroll
            for (int ct = 0; ct < 8; ++ct) {
                const int col  = ct * 16 + lr;
                const int gcol = mc * 128 + col;
                const float bi = bih[gcol], bh = bhh[gcol];
#pragma unroll
                for (int j = 0; j < 4; ++j) {
                    const int row = wrow + rt * 16 + lk * 4 + j;
                    const int n = nbase + row;
                    float gh = acc[rt][ct][j];
                    float gi = (float)g[(size_t)n * 384 + gcol];
                    if (mc == 0) {
                        rg[rt][ct][j] = fsigm(gi + gh + bi + bh);
                    } else if (mc == 1) {
                        zg[rt][ct][j] = fsigm(gi + gh + bi + bh);
                    } else {
                        float nv = ftanh(gi + bi + rg[rt][ct][j] * (gh + bh));
                        int c2 = col * 2;
                        float hold = (float)*(const _Float16*)(Xs + row * ROWB +
                            (((c2 >> 4) ^ (row & 7)) << 4) + (c2 & 15));
                        float z = zg[rt][ct][j];
                        float hn = (1.0f - z) * nv + z * hold;
                        if (relu_out) hn = fmaxf(hn, 0.0f);
                        h[(size_t)n * 128 + col] = (_Float16)hn;
                    }
                }
            }
        }
    }
}

// ---------------- segment sums (flush on id change; seg ids sorted) ----------------
__global__ __launch_bounds__(256) void seg_sum(const _Float16* __restrict__ x,
    const int* __restrict__ seg, float* __restrict__ sums, float* __restrict__ counts)
{
    int cg = threadIdx.x & 31, rs = threadIdx.x >> 5;
    int r0 = blockIdx.x * 256 + rs * 32;
    float a0 = 0, a1 = 0, a2 = 0, a3 = 0, cnt = 0;
    int cur = seg[r0];
    for (int i = 0; i < 32; ++i) {
        int n = r0 + i;
        int p = seg[n];
        if (p != cur) {
            atomicAdd(&sums[(size_t)cur * 128 + cg * 4 + 0], a0);
            atomicAdd(&sums[(size_t)cur * 128 + cg * 4 + 1], a1);
            atomicAdd(&sums[(size_t)cur * 128 + cg * 4 + 2], a2);
            atomicAdd(&sums[(size_t)cur * 128 + cg * 4 + 3], a3);
            if (cg == 0) atomicAdd(&counts[cur], cnt);
            a0 = a1 = a2 = a3 = 0; cnt = 0; cur = p;
        }
        half4v v = *(const half4v*)(x + (size_t)n * 128 + cg * 4);
        a0 += (float)v[0]; a1 += (float)v[1]; a2 += (float)v[2]; a3 += (float)v[3];
        cnt += 1.0f;
    }
    atomicAdd(&sums[(size_t)cur * 128 + cg * 4 + 0], a0);
    atomicAdd(&sums[(size_t)cur * 128 + cg * 4 + 1], a1);
    atomicAdd(&sums[(size_t)cur * 128 + cg * 4 + 2], a2);
    atomicAdd(&sums[(size_t)cur * 128 + cg * 4 + 3], a3);
    if (cg == 0) atomicAdd(&counts[cur], cnt);
}

// ---------------- gproj[p] = gmean[p] @ W_l[128:256,:] + b_l (fp32) ----------------
__global__ __launch_bounds__(256) void gproj_kernel(const float* __restrict__ sums,
    const float* __restrict__ counts, const float* __restrict__ Wl,
    const float* __restrict__ bl, float* __restrict__ gproj)
{
    __shared__ float gm[128];
    int p = blockIdx.x, m = threadIdx.x;
    if (m < 128) gm[m] = sums[(size_t)p * 128 + m] / fmaxf(counts[p], 1.0f);
    __syncthreads();
    float acc = bl[m];
#pragma unroll 8
    for (int k = 0; k < 128; ++k)
        acc = fmaf(gm[k], Wl[(size_t)(128 + k) * 256 + m], acc);
    gproj[(size_t)p * 256 + m] = acc;
}

// ---------------- final: out[n] = u2[n] . W_l3 + b_l3 ----------------
__global__ __launch_bounds__(256) void final_dot(const _Float16* __restrict__ u2,
    const float* __restrict__ wl3, const float* __restrict__ bl3, float* __restrict__ out)
{
    int gid = blockIdx.x * 256 + threadIdx.x;
    int n = gid >> 6, lane = gid & 63;
    half2v v = *(const half2v*)(u2 + (size_t)n * 128 + lane * 2);
    float s = (float)v[0] * wl3[lane * 2] + (float)v[1] * wl3[lane * 2 + 1];
#pragma unroll
    for (int off = 32; off; off >>= 1) s += __shfl_xor(s, off);
    if (lane == 0) out[n] = s + bl3[0];
}

extern "C" void kernel_launch(void* const* d_in, const int* in_sizes, int n_in,
                              void* d_out, int out_size, void* d_ws, size_t ws_size,
                              hipStream_t stream)
{
    (void)in_sizes; (void)n_in; (void)out_size; (void)ws_size;

    const float* G     = (const float*)d_in[0];
    const int*   ei    = (const int*)d_in[1];
    const float* ew    = (const float*)d_in[2];
    const int*   seg   = (const int*)d_in[4];
    const float* Wemb1 = (const float*)d_in[5];  const float* bemb1 = (const float*)d_in[6];
    const float* Wemb2 = (const float*)d_in[7];  const float* bemb2 = (const float*)d_in[8];
    const float* c1W   = (const float*)d_in[9];
    const float* c1Wih = (const float*)d_in[10]; const float* c1Whh = (const float*)d_in[11];
    const float* c1bih = (const float*)d_in[12]; const float* c1bhh = (const float*)d_in[13];
    const float* c2W   = (const float*)d_in[14];
    const float* c2Wih = (const float*)d_in[15]; const float* c2Whh = (const float*)d_in[16];
    const float* c2bih = (const float*)d_in[17]; const float* c2bhh = (const float*)d_in[18];
    const float* Wg1   = (const float*)d_in[19]; const float* bg1   = (const float*)d_in[20];
    const float* Wg2   = (const float*)d_in[21]; const float* bg2   = (const float*)d_in[22];
    const float* Wl    = (const float*)d_in[23]; const float* bl    = (const float*)d_in[24];
    const float* Wl2   = (const float*)d_in[25]; const float* bl2   = (const float*)d_in[26];
    const float* Wl3   = (const float*)d_in[27]; const float* bl3   = (const float*)d_in[28];

    const int* srcp = ei;
    const int* dstp = ei + NEDGES;

    char* ws = (char*)d_ws;
    const size_t NBH  = (size_t)NNODES * 128 * 2;   // 32MB fp16 node buffer
    const size_t G3B  = (size_t)NNODES * 384 * 2;   // 96MB gate buffer

    _Float16* hA   = (_Float16*)ws;
    _Float16* hB   = (_Float16*)(ws + NBH);
    _Float16* g    = (_Float16*)(ws + 2 * NBH);                // gi [N][384]; reused as u1 [N][256]
    _Float16* aggH = (_Float16*)(ws + 2 * NBH + G3B);          // [N][128] fp16
    char*     aux  = ws + 3 * NBH + G3B;
    float* sums   = (float*)aux;                                // 32KB
    float* counts = (float*)(aux + 32768);                      // 1KB pad
    float* gproj  = (float*)(aux + 33792);                      // 64KB
    // CSR area
    int*  deg   = (int*)(aux + 33792 + 65536);
    int*  offs  = deg + NNODES;
    int*  pos   = offs + NNODES + 64;
    int2* csr   = (int2*)(pos + NNODES);
    _Float16* wt = (_Float16*)((char*)csr + (size_t)NEDGES * 8);

    _Float16* wt_emb2 = wt;                    // [128][128]
    _Float16* wt_c1a  = wt + 16384;
    _Float16* wt_c1b  = wt + 2 * 16384;
    _Float16* wt_c2a  = wt + 3 * 16384;
    _Float16* wt_c2b  = wt + 4 * 16384;
    _Float16* wt_g1   = wt + 5 * 16384;
    _Float16* wt_g2   = wt + 6 * 16384;
    _Float16* wt_l    = wt + 7 * 16384;        // [256][128]
    _Float16* wt_l2   = wt + 7 * 16384 + 32768;        // [128][256]
    _Float16* wt_ih1  = wt + 7 * 16384 + 2 * 32768;    // [384][128]
    _Float16* wt_hh1  = wt_ih1 + 49152;
    _Float16* wt_ih2  = wt_ih1 + 2 * 49152;
    _Float16* wt_hh2  = wt_ih1 + 3 * 49152;

    // ---- weight prep ----
    tr_cvt<<<64, 256, 0, stream>>>(Wemb2, wt_emb2, 128, 128, 128);
    tr_cvt<<<64, 256, 0, stream>>>(c1W,           wt_c1a, 128, 128, 128);
    tr_cvt<<<64, 256, 0, stream>>>(c1W + 16384,   wt_c1b, 128, 128, 128);
    tr_cvt<<<64, 256, 0, stream>>>(c2W,           wt_c2a, 128, 128, 128);
    tr_cvt<<<64, 256, 0, stream>>>(c2W + 16384,   wt_c2b, 128, 128, 128);
    tr_cvt<<<64, 256, 0, stream>>>(Wg1, wt_g1, 128, 128, 128);
    tr_cvt<<<64, 256, 0, stream>>>(Wg2, wt_g2, 128, 128, 128);
    tr_cvt<<<128, 256, 0, stream>>>(Wl,  wt_l,  128, 256, 256);
    tr_cvt<<<128, 256, 0, stream>>>(Wl2, wt_l2, 256, 128, 128);
    cvt16<<<192, 256, 0, stream>>>(c1Wih, wt_ih1, 49152);
    cvt16<<<192, 256, 0, stream>>>(c1Whh, wt_hh1, 49152);
    cvt16<<<192, 256, 0, stream>>>(c2Wih, wt_ih2, 49152);
    cvt16<<<192, 256, 0, stream>>>(c2Whh, wt_hh2, 49152);

    // ---- CSR build ----
    hipMemsetAsync(deg, 0, NNODES * 4, stream);
    deg_hist<<<NEDGES / 256, 256, 0, stream>>>(dstp, deg);
    scan1<<<128, 256, 0, stream>>>(deg, offs, pos);
    scan2<<<1, 128, 0, stream>>>(pos);
    scan3<<<NNODES / 256, 256, 0, stream>>>(offs, pos, deg);
    csr_fill<<<NEDGES / 256, 256, 0, stream>>>(srcp, dstp, ew, deg, csr);

    // ---- embeddings ----
    emb1_kernel<<<NNODES * 128 / 256, 256, 0, stream>>>(G, Wemb1, bemb1, hB);
    gemm_mfma<128, 1, true, true, false><<<512, 256, 0, stream>>>(
        hB, 128, wt_emb2, bemb2, hA, 128, nullptr, nullptr);

    // ---- 2 GatedGraphConv layers x 2 GRU iterations ----
    const _Float16* convW[2][2] = { { wt_c1a, wt_c1b }, { wt_c2a, wt_c2b } };
    const _Float16* wih[2] = { wt_ih1, wt_ih2 };
    const _Float16* whh[2] = { wt_hh1, wt_hh2 };
    const float* bihs[2] = { c1bih, c2bih };
    const float* bhhs[2] = { c1bhh, c2bhh };
    for (int cv = 0; cv < 2; ++cv) {
        for (int lyr = 0; lyr < 2; ++lyr) {
            gemm_mfma<128, 1, true, false, false><<<512, 256, 0, stream>>>(
                hA, 128, convW[cv][lyr], nullptr, hB, 128, nullptr, nullptr);
            gather_agg<<<NNODES / 4, 256, 0, stream>>>(hB, csr, offs, aggH);
            gemm_mfma<128, 3, true, false, false><<<512, 256, 0, stream>>>(
                aggH, 128, wih[cv], nullptr, g, 384, nullptr, nullptr);
            gemm_gru<<<512, 256, 0, stream>>>(
                hA, whh[cv], g, bihs[cv], bhhs[cv], (lyr == 1) ? 1 : 0);
        }
    }

    // ---- head MLP ----
    gemm_mfma<128, 1, true, true, false><<<512, 256, 0, stream>>>(
        hA, 128, wt_g1, bg1, hB, 128, nullptr, nullptr);
    gemm_mfma<128, 1, true, false, false><<<512, 256, 0, stream>>>(
        hB, 128, wt_g2, bg2, hA, 128, nullptr, nullptr);

    // ---- segment mean -> gproj ----
    hipMemsetAsync(sums, 0, 33792, stream);
    seg_sum<<<NNODES / 256, 256, 0, stream>>>(hA, seg, sums, counts);
    gproj_kernel<<<NPROB, 256, 0, stream>>>(sums, counts, Wl, bl, gproj);

    // ---- u1 = relu(x @ Wl_top + gproj[seg]) [N,256] ----
    gemm_mfma<128, 2, true, true, true><<<512, 256, 0, stream>>>(
        hA, 128, wt_l, nullptr, g, 256, gproj, seg);
    // ---- u2 = relu(u1 @ W_l2 + b_l2) [N,128] ----
    gemm_mfma<256, 1, true, true, false><<<256, 256, 0, stream>>>(
        g, 256, wt_l2, bl2, hB, 128, nullptr, nullptr);
    // ---- out ----
    final_dot<<<NNODES * 64 / 256, 256, 0, stream>>>(hB, Wl3, bl3, (float*)d_out);
}

// Round 5
// 1102.174 us; speedup vs baseline: 6.0718x; 1.6899x over previous
//
#include <hip/hip_runtime.h>
#include <cstdint>
#include <cstddef>

#define NNODES 131072
#define NEDGES 1048576
#define NPROB  64

typedef _Float16 half8 __attribute__((ext_vector_type(8)));
typedef _Float16 half4v __attribute__((ext_vector_type(4)));
typedef _Float16 half2v __attribute__((ext_vector_type(2)));
typedef float float4v __attribute__((ext_vector_type(4)));

__device__ __forceinline__ float fsigm(float x) {
    return __builtin_amdgcn_rcpf(1.0f + __expf(-x));
}
__device__ __forceinline__ float ftanh(float x) {
    return 1.0f - 2.0f * __builtin_amdgcn_rcpf(__expf(2.0f * x) + 1.0f);
}

__device__ __forceinline__ void async16(void* lds, const void* g) {
    __builtin_amdgcn_global_load_lds(
        (const __attribute__((address_space(1))) uint32_t*)g,
        (__attribute__((address_space(3))) uint32_t*)lds, 16, 0, 0);
}

// ---------------- weight prep: fp32 -> fp16 (optionally transposed) ----------------
__global__ __launch_bounds__(256) void cvt16(const float* __restrict__ s,
                                             _Float16* __restrict__ d, int n)
{
    int i = blockIdx.x * 256 + threadIdx.x;
    if (i < n) d[i] = (_Float16)s[i];
}

// dst[m*K + k] = src[k*sstride + m]   (dst is [M][K] fp16)
__global__ __launch_bounds__(256) void tr_cvt(const float* __restrict__ src,
    _Float16* __restrict__ dst, int K, int M, int sstride)
{
    int i = blockIdx.x * 256 + threadIdx.x;
    if (i < M * K) {
        int m = i / K, k = i % K;
        dst[i] = (_Float16)src[(size_t)k * sstride + m];
    }
}

// ---------------- CSR build: histogram -> scan -> fill ----------------
__global__ __launch_bounds__(256) void deg_hist(const int* __restrict__ dst,
                                                int* __restrict__ deg)
{
    int e = blockIdx.x * 256 + threadIdx.x;
    atomicAdd(&deg[dst[e]], 1);
}

__global__ __launch_bounds__(256) void scan1(const int* __restrict__ deg,
    int* __restrict__ offs, int* __restrict__ bsum)
{
    __shared__ int s[256];
    int b = blockIdx.x, tid = threadIdx.x;
    int4 v = ((const int4*)deg)[b * 256 + tid];
    int t0 = v.x, t1 = t0 + v.y, t2 = t1 + v.z, t3 = t2 + v.w;
    s[tid] = t3;
    __syncthreads();
    for (int off = 1; off < 256; off <<= 1) {
        int x = (tid >= off) ? s[tid - off] : 0;
        __syncthreads();
        if (tid >= off) s[tid] += x;
        __syncthreads();
    }
    int excl = tid ? s[tid - 1] : 0;
    int4 o; o.x = excl; o.y = excl + t0; o.z = excl + t1; o.w = excl + t2;
    ((int4*)offs)[b * 256 + tid] = o;
    if (tid == 255) bsum[b] = s[255];
}

__global__ __launch_bounds__(128) void scan2(int* __restrict__ bsum)
{
    __shared__ int s[128];
    int tid = threadIdx.x;
    s[tid] = bsum[tid];
    __syncthreads();
    for (int off = 1; off < 128; off <<= 1) {
        int x = (tid >= off) ? s[tid - off] : 0;
        __syncthreads();
        if (tid >= off) s[tid] += x;
        __syncthreads();
    }
    bsum[tid] = tid ? s[tid - 1] : 0;
}

__global__ __launch_bounds__(256) void scan3(int* __restrict__ offs,
    const int* __restrict__ bsum, int* __restrict__ pos)
{
    int i = blockIdx.x * 256 + threadIdx.x;
    int v = offs[i] + bsum[i >> 10];
    offs[i] = v;
    pos[i] = v;
    if (i == 0) offs[NNODES] = NEDGES;
}

__global__ __launch_bounds__(256) void csr_fill(const int* __restrict__ src,
    const int* __restrict__ dst, const float* __restrict__ ew,
    int* __restrict__ pos, int2* __restrict__ csr)
{
    int e = blockIdx.x * 256 + threadIdx.x;
    int slot = atomicAdd(&pos[dst[e]], 1);
    csr[slot] = make_int2(src[e], __float_as_int(ew[e]));
}

// ---------------- gather aggregate: agg[n] = sum_{e: dst=n} t[src_e] * w_e ------
__global__ __launch_bounds__(256) void gather_agg(const _Float16* __restrict__ t,
    const int2* __restrict__ csr, const int* __restrict__ offs,
    _Float16* __restrict__ agg)
{
    int node = blockIdx.x * 4 + (threadIdx.x >> 6);
    int lane = threadIdx.x & 63;
    int i = offs[node], end = offs[node + 1];
    float a0 = 0.0f, a1 = 0.0f;
    int2 p;
    if (i < end) p = csr[i];
    while (i < end) {
        int2 cur = p;
        if (i + 1 < end) p = csr[i + 1];
        float w = __int_as_float(cur.y);
        half2v v = *(const half2v*)(t + (size_t)cur.x * 128 + lane * 2);
        a0 = fmaf((float)v[0], w, a0);
        a1 = fmaf((float)v[1], w, a1);
        ++i;
    }
    half2v o; o[0] = (_Float16)a0; o[1] = (_Float16)a1;
    *(half2v*)(agg + (size_t)node * 128 + lane * 2) = o;
}

// ---------------- emb1: x = relu(G @ W1 + b1) -> fp16 ----------------
__global__ __launch_bounds__(256) void emb1_kernel(const float* __restrict__ G,
    const float* __restrict__ W1, const float* __restrict__ b1, _Float16* __restrict__ Y)
{
    int idx = blockIdx.x * 256 + threadIdx.x;
    int n = idx >> 7, c = idx & 127;
    const float* g = G + (size_t)n * 8;
    float y = b1[c];
#pragma unroll
    for (int k = 0; k < 8; ++k) y = fmaf(g[k], W1[k * 128 + c], y);
    Y[(size_t)n * 128 + c] = (_Float16)fmaxf(y, 0.0f);
}

// ---------------- MFMA GEMM: out = act(X @ WtT + bias [+gproj]) ----------------
template<int K, int MCH, bool INF16, bool RELU, bool SEGADD>
__global__ __launch_bounds__(256, 2) void gemm_mfma(
    const void* __restrict__ Xin, int xstride,
    const _Float16* __restrict__ Wt,
    const float* __restrict__ bias,
    _Float16* __restrict__ out1, int ostride,
    const float* __restrict__ gproj, const int* __restrict__ seg)
{
    constexpr int ROWB = 2 * K;     // LDS row bytes
    constexpr int SPR  = K / 8;     // 16B slots per row
    __shared__ __align__(16) char Xs[128 * ROWB];
    __shared__ __align__(16) char Ws[128 * ROWB];
    const int tid = threadIdx.x, wid = tid >> 6, l = tid & 63;
    const int lr = l & 15, lk = l >> 4;
    const int wrow = wid * 32;

    for (int mc = 0; mc < MCH; ++mc) {
        __syncthreads();
        {   // stage W chunk [128][K]
            const _Float16* wsrc = Wt + (size_t)mc * 128 * K;
            for (int s0 = wid * 64; s0 < 128 * SPR; s0 += 256) {
                int s = s0 + l;
                int row = s / SPR, sub = s % SPR;
                int ksub = sub ^ (row & 7);
                async16(Ws + s0 * 16, (const char*)(wsrc + (size_t)row * K) + ksub * 16);
            }
        }
        asm volatile("s_waitcnt vmcnt(0)" ::: "memory");
        __syncthreads();

        half8 bfr[32];
        if constexpr (K == 128) {
#pragma unroll
            for (int ct = 0; ct < 8; ++ct)
#pragma unroll
                for (int ks = 0; ks < 4; ++ks) {
                    int row = ct * 16 + lr;
                    bfr[ct * 4 + ks] = *(const half8*)(Ws + row * ROWB +
                        ((ks * 64 + lk * 16) ^ ((row & 7) << 4)));
                }
        }

        for (int t = blockIdx.x; t < NNODES / 128; t += gridDim.x) {
            const int nbase = t * 128;
            __syncthreads();
            if constexpr (INF16) {
                const _Float16* xsrc = (const _Float16*)Xin;
                for (int s0 = wid * 64; s0 < 128 * SPR; s0 += 256) {
                    int s = s0 + l;
                    int row = s / SPR, sub = s % SPR;
                    int ksub = sub ^ (row & 7);
                    async16(Xs + s0 * 16,
                            (const char*)(xsrc + (size_t)(nbase + row) * xstride) + ksub * 16);
                }
                asm volatile("s_waitcnt vmcnt(0)" ::: "memory");
            } else {
                const float* xsrc = (const float*)Xin;
                for (int s = tid; s < 128 * SPR; s += 256) {
                    int row = s / SPR, sub = s % SPR;
                    int ksub = sub ^ (row & 7);
                    const float* p = xsrc + (size_t)(nbase + row) * xstride + ksub * 8;
                    float4 u = ((const float4*)p)[0];
                    float4 v = ((const float4*)p)[1];
                    half8 hv;
                    hv[0] = (_Float16)u.x; hv[1] = (_Float16)u.y;
                    hv[2] = (_Float16)u.z; hv[3] = (_Float16)u.w;
                    hv[4] = (_Float16)v.x; hv[5] = (_Float16)v.y;
                    hv[6] = (_Float16)v.z; hv[7] = (_Float16)v.w;
                    *(half8*)(Xs + s * 16) = hv;
                }
            }
            __syncthreads();

            float4v acc[2][8];
#pragma unroll
            for (int i = 0; i < 2; ++i)
#pragma unroll
                for (int j = 0; j < 8; ++j)
#pragma unroll
                    for (int q = 0; q < 4; ++q) acc[i][j][q] = 0.0f;

            if constexpr (K == 128) {
#pragma unroll
                for (int rt = 0; rt < 2; ++rt) {
                    half8 a[4];
                    int row = wrow + rt * 16 + lr;
#pragma unroll
                    for (int ks = 0; ks < 4; ++ks)
                        a[ks] = *(const half8*)(Xs + row * ROWB +
                            ((ks * 64 + lk * 16) ^ ((row & 7) << 4)));
#pragma unroll
                    for (int ct = 0; ct < 8; ++ct)
#pragma unroll
                        for (int ks = 0; ks < 4; ++ks)
                            acc[rt][ct] = __builtin_amdgcn_mfma_f32_16x16x32_f16(
                                a[ks], bfr[ct * 4 + ks], acc[rt][ct], 0, 0, 0);
                }
            } else {   // K == 256
#pragma unroll
                for (int kc = 0; kc < 2; ++kc) {
#pragma unroll
                    for (int ct = 0; ct < 8; ++ct)
#pragma unroll
                        for (int ks = 0; ks < 4; ++ks) {
                            int row = ct * 16 + lr;
                            bfr[ct * 4 + ks] = *(const half8*)(Ws + row * ROWB +
                                (((kc * 4 + ks) * 64 + lk * 16) ^ ((row & 7) << 4)));
                        }
#pragma unroll
                    for (int rt = 0; rt < 2; ++rt) {
                        half8 a[4];
                        int row = wrow + rt * 16 + lr;
#pragma unroll
                        for (int ks = 0; ks < 4; ++ks)
                            a[ks] = *(const half8*)(Xs + row * ROWB +
                                (((kc * 4 + ks) * 64 + lk * 16) ^ ((row & 7) << 4)));
#pragma unroll
                        for (int ct = 0; ct < 8; ++ct)
#pragma unroll
                            for (int ks = 0; ks < 4; ++ks)
                                acc[rt][ct] = __builtin_amdgcn_mfma_f32_16x16x32_f16(
                                    a[ks], bfr[ct * 4 + ks], acc[rt][ct], 0, 0, 0);
                    }
                }
            }

#pragma unroll
            for (int rt = 0; rt < 2; ++rt)
#pragma unroll
            for (int ct = 0; ct < 8; ++ct) {
                const int col = ct * 16 + lr;
                float bv = 0.0f;
                if (bias) bv = bias[mc * 128 + col];
#pragma unroll
                for (int j = 0; j < 4; ++j) {
                    const int n = nbase + wrow + rt * 16 + lk * 4 + j;
                    float v = acc[rt][ct][j] + bv;
                    if constexpr (SEGADD)
                        v += gproj[(size_t)seg[n] * 256 + mc * 128 + col];
                    if constexpr (RELU) v = fmaxf(v, 0.0f);
                    out1[(size_t)n * ostride + mc * 128 + col] = (_Float16)v;
                }
            }
        }
    }
}

// ---------------- fully-fused GRU: h' = GRUCell(agg@Wih.T+bih, h@Whh.T+bhh) -------
// One 128-node tile per block. 8 waves in 4x2 grid: wave owns 32 rows x 64 cols.
// 6 weight chunks (ih_r,hh_r,ih_z,hh_z,ih_n,hh_n) streamed through a double-
// buffered LDS slot; chunk c+1 prefetch overlaps MFMA on chunk c. No gi buffer.
__global__ __launch_bounds__(512, 2) void gru_fused(
    const _Float16* __restrict__ agg,   // [N][128]
    _Float16* h,                        // [N][128] in/out
    const _Float16* __restrict__ Wih,   // [384][128] fp16
    const _Float16* __restrict__ Whh,   // [384][128] fp16
    const float* __restrict__ bih, const float* __restrict__ bhh,
    int relu_out)
{
    __shared__ __align__(16) char As[128 * 256];
    __shared__ __align__(16) char Hs[128 * 256];
    __shared__ __align__(16) char Wb[2][128 * 256];
    const int tid = threadIdx.x, wid = tid >> 6, l = tid & 63;
    const int lr = l & 15, lk = l >> 4;
    const int wr = wid >> 1, wc = wid & 1;       // 4 row-groups x 2 col-groups
    const int nbase = blockIdx.x * 128;

    // stage a [128][128] fp16 tile (source pre-swizzled -> linear LDS dest)
    auto stageT = [&](char* dst, const _Float16* src) {
        for (int s0 = wid * 64; s0 < 2048; s0 += 512) {
            int s = s0 + l;
            int row = s >> 4, sub = s & 15;
            int ksub = sub ^ (row & 7);
            async16(dst + s0 * 16, (const char*)(src + (size_t)row * 128) + ksub * 16);
        }
    };

    stageT(As, agg + (size_t)nbase * 128);
    stageT(Hs, h + (size_t)nbase * 128);
    stageT(Wb[0], Wih);                          // chunk 0 = ih_r

    float4v accA[2][4], accB[2][4], rg[2][4], zg[2][4];
    half8 aAg[2][4], aH[2][4];

#pragma unroll
    for (int c = 0; c < 6; ++c) {
        asm volatile("s_waitcnt vmcnt(0)" ::: "memory");
        __syncthreads();
        if (c < 5) {   // prefetch next chunk into other buffer (overlaps MFMA below)
            const int nc = c + 1;
            const _Float16* wsrc = ((nc & 1) ? Whh : Wih) + (size_t)(nc >> 1) * 16384;
            stageT(Wb[nc & 1], wsrc);
        }
        if (c == 0) {  // A-frags for both tiles (As/Hs ready; live whole kernel)
#pragma unroll
            for (int rt = 0; rt < 2; ++rt) {
                const int row = wr * 32 + rt * 16 + lr;
#pragma unroll
                for (int ks = 0; ks < 4; ++ks) {
                    const int off = row * 256 + ((ks * 64 + lk * 16) ^ ((row & 7) << 4));
                    aAg[rt][ks] = *(const half8*)(As + off);
                    aH[rt][ks]  = *(const half8*)(Hs + off);
                }
            }
        }

        auto& af  = (c & 1) ? aH : aAg;
        auto& acc = (c & 1) ? accB : accA;
#pragma unroll
        for (int rt = 0; rt < 2; ++rt)
#pragma unroll
            for (int ct = 0; ct < 4; ++ct)
#pragma unroll
                for (int q = 0; q < 4; ++q) acc[rt][ct][q] = 0.0f;

        const char* wb = Wb[c & 1];
#pragma unroll
        for (int ct = 0; ct < 4; ++ct) {
            const int rowb = wc * 64 + ct * 16 + lr;
#pragma unroll
            for (int ks = 0; ks < 4; ++ks) {
                half8 b = *(const half8*)(wb + rowb * 256 +
                    ((ks * 64 + lk * 16) ^ ((rowb & 7) << 4)));
                acc[0][ct] = __builtin_amdgcn_mfma_f32_16x16x32_f16(af[0][ks], b, acc[0][ct], 0, 0, 0);
                acc[1][ct] = __builtin_amdgcn_mfma_f32_16x16x32_f16(af[1][ks], b, acc[1][ct], 0, 0, 0);
            }
        }

        if (c == 1) {          // r = sigm(gi_r + gh_r + bih_r + bhh_r)
#pragma unroll
            for (int rt = 0; rt < 2; ++rt)
#pragma unroll
            for (int ct = 0; ct < 4; ++ct) {
                const int col = wc * 64 + ct * 16 + lr;
                const float bb = bih[col] + bhh[col];
#pragma unroll
                for (int j = 0; j < 4; ++j)
                    rg[rt][ct][j] = fsigm(accA[rt][ct][j] + accB[rt][ct][j] + bb);
            }
        } else if (c == 3) {   // z
#pragma unroll
            for (int rt = 0; rt < 2; ++rt)
#pragma unroll
            for (int ct = 0; ct < 4; ++ct) {
                const int col = wc * 64 + ct * 16 + lr;
                const float bb = bih[128 + col] + bhh[128 + col];
#pragma unroll
                for (int j = 0; j < 4; ++j)
                    zg[rt][ct][j] = fsigm(accA[rt][ct][j] + accB[rt][ct][j] + bb);
            }
        } else if (c == 5) {   // n + combine + in-place write
#pragma unroll
            for (int rt = 0; rt < 2; ++rt)
#pragma unroll
            for (int ct = 0; ct < 4; ++ct) {
                const int col = wc * 64 + ct * 16 + lr;
                const float bi = bih[256 + col], bh = bhh[256 + col];
                const int c2 = col * 2;
#pragma unroll
                for (int j = 0; j < 4; ++j) {
                    const int row = wr * 32 + rt * 16 + lk * 4 + j;
                    const int n = nbase + row;
                    float nv = ftanh(accA[rt][ct][j] + bi +
                                     rg[rt][ct][j] * (accB[rt][ct][j] + bh));
                    float hold = (float)*(const _Float16*)(Hs + row * 256 +
                        (((c2 >> 4) ^ (row & 7)) << 4) + (c2 & 15));
                    float z = zg[rt][ct][j];
                    float hn = (1.0f - z) * nv + z * hold;
                    if (relu_out) hn = fmaxf(hn, 0.0f);
                    h[(size_t)n * 128 + col] = (_Float16)hn;
                }
            }
        }
    }
}

// ---------------- segment sums (flush on id change; seg ids sorted) ----------------
__global__ __launch_bounds__(256) void seg_sum(const _Float16* __restrict__ x,
    const int* __restrict__ seg, float* __restrict__ sums, float* __restrict__ counts)
{
    int cg = threadIdx.x & 31, rs = threadIdx.x >> 5;
    int r0 = blockIdx.x * 256 + rs * 32;
    float a0 = 0, a1 = 0, a2 = 0, a3 = 0, cnt = 0;
    int cur = seg[r0];
    for (int i = 0; i < 32; ++i) {
        int n = r0 + i;
        int p = seg[n];
        if (p != cur) {
            atomicAdd(&sums[(size_t)cur * 128 + cg * 4 + 0], a0);
            atomicAdd(&sums[(size_t)cur * 128 + cg * 4 + 1], a1);
            atomicAdd(&sums[(size_t)cur * 128 + cg * 4 + 2], a2);
            atomicAdd(&sums[(size_t)cur * 128 + cg * 4 + 3], a3);
            if (cg == 0) atomicAdd(&counts[cur], cnt);
            a0 = a1 = a2 = a3 = 0; cnt = 0; cur = p;
        }
        half4v v = *(const half4v*)(x + (size_t)n * 128 + cg * 4);
        a0 += (float)v[0]; a1 += (float)v[1]; a2 += (float)v[2]; a3 += (float)v[3];
        cnt += 1.0f;
    }
    atomicAdd(&sums[(size_t)cur * 128 + cg * 4 + 0], a0);
    atomicAdd(&sums[(size_t)cur * 128 + cg * 4 + 1], a1);
    atomicAdd(&sums[(size_t)cur * 128 + cg * 4 + 2], a2);
    atomicAdd(&sums[(size_t)cur * 128 + cg * 4 + 3], a3);
    if (cg == 0) atomicAdd(&counts[cur], cnt);
}

// ---------------- gproj[p] = gmean[p] @ W_l[128:256,:] + b_l (fp32) ----------------
__global__ __launch_bounds__(256) void gproj_kernel(const float* __restrict__ sums,
    const float* __restrict__ counts, const float* __restrict__ Wl,
    const float* __restrict__ bl, float* __restrict__ gproj)
{
    __shared__ float gm[128];
    int p = blockIdx.x, m = threadIdx.x;
    if (m < 128) gm[m] = sums[(size_t)p * 128 + m] / fmaxf(counts[p], 1.0f);
    __syncthreads();
    float acc = bl[m];
#pragma unroll 8
    for (int k = 0; k < 128; ++k)
        acc = fmaf(gm[k], Wl[(size_t)(128 + k) * 256 + m], acc);
    gproj[(size_t)p * 256 + m] = acc;
}

// ---------------- final: out[n] = u2[n] . W_l3 + b_l3 ----------------
__global__ __launch_bounds__(256) void final_dot(const _Float16* __restrict__ u2,
    const float* __restrict__ wl3, const float* __restrict__ bl3, float* __restrict__ out)
{
    int gid = blockIdx.x * 256 + threadIdx.x;
    int n = gid >> 6, lane = gid & 63;
    half2v v = *(const half2v*)(u2 + (size_t)n * 128 + lane * 2);
    float s = (float)v[0] * wl3[lane * 2] + (float)v[1] * wl3[lane * 2 + 1];
#pragma unroll
    for (int off = 32; off; off >>= 1) s += __shfl_xor(s, off);
    if (lane == 0) out[n] = s + bl3[0];
}

extern "C" void kernel_launch(void* const* d_in, const int* in_sizes, int n_in,
                              void* d_out, int out_size, void* d_ws, size_t ws_size,
                              hipStream_t stream)
{
    (void)in_sizes; (void)n_in; (void)out_size; (void)ws_size;

    const float* G     = (const float*)d_in[0];
    const int*   ei    = (const int*)d_in[1];
    const float* ew    = (const float*)d_in[2];
    const int*   seg   = (const int*)d_in[4];
    const float* Wemb1 = (const float*)d_in[5];  const float* bemb1 = (const float*)d_in[6];
    const float* Wemb2 = (const float*)d_in[7];  const float* bemb2 = (const float*)d_in[8];
    const float* c1W   = (const float*)d_in[9];
    const float* c1Wih = (const float*)d_in[10]; const float* c1Whh = (const float*)d_in[11];
    const float* c1bih = (const float*)d_in[12]; const float* c1bhh = (const float*)d_in[13];
    const float* c2W   = (const float*)d_in[14];
    const float* c2Wih = (const float*)d_in[15]; const float* c2Whh = (const float*)d_in[16];
    const float* c2bih = (const float*)d_in[17]; const float* c2bhh = (const float*)d_in[18];
    const float* Wg1   = (const float*)d_in[19]; const float* bg1   = (const float*)d_in[20];
    const float* Wg2   = (const float*)d_in[21]; const float* bg2   = (const float*)d_in[22];
    const float* Wl    = (const float*)d_in[23]; const float* bl    = (const float*)d_in[24];
    const float* Wl2   = (const float*)d_in[25]; const float* bl2   = (const float*)d_in[26];
    const float* Wl3   = (const float*)d_in[27]; const float* bl3   = (const float*)d_in[28];

    const int* srcp = ei;
    const int* dstp = ei + NEDGES;

    char* ws = (char*)d_ws;
    const size_t NBH  = (size_t)NNODES * 128 * 2;   // 32MB fp16 node buffer
    const size_t G3B  = (size_t)NNODES * 384 * 2;   // 96MB (u1 area + slack)

    _Float16* hA   = (_Float16*)ws;
    _Float16* hB   = (_Float16*)(ws + NBH);
    _Float16* g    = (_Float16*)(ws + 2 * NBH);                // u1 [N][256]
    _Float16* aggH = (_Float16*)(ws + 2 * NBH + G3B);          // [N][128] fp16
    char*     aux  = ws + 3 * NBH + G3B;
    float* sums   = (float*)aux;                                // 32KB
    float* counts = (float*)(aux + 32768);                      // 1KB pad
    float* gproj  = (float*)(aux + 33792);                      // 64KB
    // CSR area
    int*  deg   = (int*)(aux + 33792 + 65536);
    int*  offs  = deg + NNODES;
    int*  pos   = offs + NNODES + 64;
    int2* csr   = (int2*)(pos + NNODES);
    _Float16* wt = (_Float16*)((char*)csr + (size_t)NEDGES * 8);

    _Float16* wt_emb2 = wt;                    // [128][128]
    _Float16* wt_c1a  = wt + 16384;
    _Float16* wt_c1b  = wt + 2 * 16384;
    _Float16* wt_c2a  = wt + 3 * 16384;
    _Float16* wt_c2b  = wt + 4 * 16384;
    _Float16* wt_g1   = wt + 5 * 16384;
    _Float16* wt_g2   = wt + 6 * 16384;
    _Float16* wt_l    = wt + 7 * 16384;        // [256][128]
    _Float16* wt_l2   = wt + 7 * 16384 + 32768;        // [128][256]
    _Float16* wt_ih1  = wt + 7 * 16384 + 2 * 32768;    // [384][128]
    _Float16* wt_hh1  = wt_ih1 + 49152;
    _Float16* wt_ih2  = wt_ih1 + 2 * 49152;
    _Float16* wt_hh2  = wt_ih1 + 3 * 49152;

    // ---- weight prep ----
    tr_cvt<<<64, 256, 0, stream>>>(Wemb2, wt_emb2, 128, 128, 128);
    tr_cvt<<<64, 256, 0, stream>>>(c1W,           wt_c1a, 128, 128, 128);
    tr_cvt<<<64, 256, 0, stream>>>(c1W + 16384,   wt_c1b, 128, 128, 128);
    tr_cvt<<<64, 256, 0, stream>>>(c2W,           wt_c2a, 128, 128, 128);
    tr_cvt<<<64, 256, 0, stream>>>(c2W + 16384,   wt_c2b, 128, 128, 128);
    tr_cvt<<<64, 256, 0, stream>>>(Wg1, wt_g1, 128, 128, 128);
    tr_cvt<<<64, 256, 0, stream>>>(Wg2, wt_g2, 128, 128, 128);
    tr_cvt<<<128, 256, 0, stream>>>(Wl,  wt_l,  128, 256, 256);
    tr_cvt<<<128, 256, 0, stream>>>(Wl2, wt_l2, 256, 128, 128);
    cvt16<<<192, 256, 0, stream>>>(c1Wih, wt_ih1, 49152);
    cvt16<<<192, 256, 0, stream>>>(c1Whh, wt_hh1, 49152);
    cvt16<<<192, 256, 0, stream>>>(c2Wih, wt_ih2, 49152);
    cvt16<<<192, 256, 0, stream>>>(c2Whh, wt_hh2, 49152);

    // ---- CSR build ----
    hipMemsetAsync(deg, 0, NNODES * 4, stream);
    deg_hist<<<NEDGES / 256, 256, 0, stream>>>(dstp, deg);
    scan1<<<128, 256, 0, stream>>>(deg, offs, pos);
    scan2<<<1, 128, 0, stream>>>(pos);
    scan3<<<NNODES / 256, 256, 0, stream>>>(offs, pos, deg);
    csr_fill<<<NEDGES / 256, 256, 0, stream>>>(srcp, dstp, ew, deg, csr);

    // ---- embeddings ----
    emb1_kernel<<<NNODES * 128 / 256, 256, 0, stream>>>(G, Wemb1, bemb1, hB);
    gemm_mfma<128, 1, true, true, false><<<512, 256, 0, stream>>>(
        hB, 128, wt_emb2, bemb2, hA, 128, nullptr, nullptr);

    // ---- 2 GatedGraphConv layers x 2 GRU iterations ----
    const _Float16* convW[2][2] = { { wt_c1a, wt_c1b }, { wt_c2a, wt_c2b } };
    const _Float16* wih[2] = { wt_ih1, wt_ih2 };
    const _Float16* whh[2] = { wt_hh1, wt_hh2 };
    const float* bihs[2] = { c1bih, c2bih };
    const float* bhhs[2] = { c1bhh, c2bhh };
    for (int cv = 0; cv < 2; ++cv) {
        for (int lyr = 0; lyr < 2; ++lyr) {
            gemm_mfma<128, 1, true, false, false><<<512, 256, 0, stream>>>(
                hA, 128, convW[cv][lyr], nullptr, hB, 128, nullptr, nullptr);
            gather_agg<<<NNODES / 4, 256, 0, stream>>>(hB, csr, offs, aggH);
            gru_fused<<<NNODES / 128, 512, 0, stream>>>(
                aggH, hA, wih[cv], whh[cv], bihs[cv], bhhs[cv], (lyr == 1) ? 1 : 0);
        }
    }

    // ---- head MLP ----
    gemm_mfma<128, 1, true, true, false><<<512, 256, 0, stream>>>(
        hA, 128, wt_g1, bg1, hB, 128, nullptr, nullptr);
    gemm_mfma<128, 1, true, false, false><<<512, 256, 0, stream>>>(
        hB, 128, wt_g2, bg2, hA, 128, nullptr, nullptr);

    // ---- segment mean -> gproj ----
    hipMemsetAsync(sums, 0, 33792, stream);
    seg_sum<<<NNODES / 256, 256, 0, stream>>>(hA, seg, sums, counts);
    gproj_kernel<<<NPROB, 256, 0, stream>>>(sums, counts, Wl, bl, gproj);

    // ---- u1 = relu(x @ Wl_top + gproj[seg]) [N,256] ----
    gemm_mfma<128, 2, true, true, true><<<512, 256, 0, stream>>>(
        hA, 128, wt_l, nullptr, g, 256, gproj, seg);
    // ---- u2 = relu(u1 @ W_l2 + b_l2) [N,128] ----
    gemm_mfma<256, 1, true, true, false><<<256, 256, 0, stream>>>(
        g, 256, wt_l2, bl2, hB, 128, nullptr, nullptr);
    // ---- out ----
    final_dot<<<NNODES * 64 / 256, 256, 0, stream>>>(hB, Wl3, bl3, (float*)d_out);
}

// Round 6
// 968.684 us; speedup vs baseline: 6.9086x; 1.1378x over previous
//
#include <hip/hip_runtime.h>
#include <cstdint>
#include <cstddef>

#define NNODES 131072
#define NEDGES 1048576
#define NPROB  64

typedef _Float16 half8 __attribute__((ext_vector_type(8)));
typedef _Float16 half4v __attribute__((ext_vector_type(4)));
typedef _Float16 half2v __attribute__((ext_vector_type(2)));
typedef float float4v __attribute__((ext_vector_type(4)));

__device__ __forceinline__ float fsigm(float x) {
    return __builtin_amdgcn_rcpf(1.0f + __expf(-x));
}
__device__ __forceinline__ float ftanh(float x) {
    return 1.0f - 2.0f * __builtin_amdgcn_rcpf(__expf(2.0f * x) + 1.0f);
}

__device__ __forceinline__ void async16(void* lds, const void* g) {
    __builtin_amdgcn_global_load_lds(
        (const __attribute__((address_space(1))) uint32_t*)g,
        (__attribute__((address_space(3))) uint32_t*)lds, 16, 0, 0);
}

// ---------------- weight prep ----------------
__global__ __launch_bounds__(256) void cvt16(const float* __restrict__ s,
                                             _Float16* __restrict__ d, int n)
{
    int i = blockIdx.x * 256 + threadIdx.x;
    if (i < n) d[i] = (_Float16)s[i];
}

// dst[m*K + k] = src[k*sstride + m]
__global__ __launch_bounds__(256) void tr_cvt(const float* __restrict__ src,
    _Float16* __restrict__ dst, int K, int M, int sstride)
{
    int i = blockIdx.x * 256 + threadIdx.x;
    if (i < M * K) {
        int m = i / K, k = i % K;
        dst[i] = (_Float16)src[(size_t)k * sstride + m];
    }
}

// Wc[g][j] = sum_k Wih[g][k] * W[j][k]   (both rows contiguous)  -> fp16 [384][128]
__global__ __launch_bounds__(256) void combine_gru(const float* __restrict__ Wih,
    const float* __restrict__ W, _Float16* __restrict__ outw)
{
    int i = blockIdx.x * 256 + threadIdx.x;   // 49152
    int g = i >> 7, j = i & 127;
    const float* a = Wih + (size_t)g * 128;
    const float* b = W + (size_t)j * 128;
    float s = 0.0f;
#pragma unroll 8
    for (int k = 0; k < 128; ++k) s = fmaf(a[k], b[k], s);
    outw[i] = (_Float16)s;
}

// At[m][j] = sum_k Wg2[j][k] * Wl[k][m]   -> fp16 [256][128]  (m in [0,256))
__global__ __launch_bounds__(256) void combine_headA(const float* __restrict__ Wg2,
    const float* __restrict__ Wl, _Float16* __restrict__ At)
{
    int i = blockIdx.x * 256 + threadIdx.x;   // 32768
    int m = i >> 7, j = i & 127;
    float s = 0.0f;
#pragma unroll 8
    for (int k = 0; k < 128; ++k)
        s = fmaf(Wg2[(size_t)j * 128 + k], Wl[(size_t)k * 256 + m], s);
    At[i] = (_Float16)s;
}

// Bf[t][m] = sum_k Wg2[t][k] * Wl[128+k][m]   -> fp32 [128][256]
__global__ __launch_bounds__(256) void combine_headB(const float* __restrict__ Wg2,
    const float* __restrict__ Wl, float* __restrict__ Bf)
{
    int i = blockIdx.x * 256 + threadIdx.x;   // 32768
    int t = i >> 8, m = i & 255;
    float s = 0.0f;
#pragma unroll 8
    for (int k = 0; k < 128; ++k)
        s = fmaf(Wg2[(size_t)t * 128 + k], Wl[(size_t)(128 + k) * 256 + m], s);
    Bf[i] = s;
}

// cvec[m] = bl[m] + sum_k bg2[k]*(Wl[k][m] + Wl[128+k][m])
__global__ __launch_bounds__(256) void combine_c(const float* __restrict__ bg2,
    const float* __restrict__ Wl, const float* __restrict__ bl, float* __restrict__ cvec)
{
    int m = threadIdx.x;
    float s = bl[m];
#pragma unroll 8
    for (int k = 0; k < 128; ++k)
        s = fmaf(bg2[k], Wl[(size_t)k * 256 + m] + Wl[(size_t)(128 + k) * 256 + m], s);
    cvec[m] = s;
}

// ---------------- CSR build: histogram -> scan -> fill ----------------
__global__ __launch_bounds__(256) void deg_hist(const int* __restrict__ dst,
                                                int* __restrict__ deg)
{
    int e = blockIdx.x * 256 + threadIdx.x;
    atomicAdd(&deg[dst[e]], 1);
}

__global__ __launch_bounds__(256) void scan1(const int* __restrict__ deg,
    int* __restrict__ offs, int* __restrict__ bsum)
{
    __shared__ int s[256];
    int b = blockIdx.x, tid = threadIdx.x;
    int4 v = ((const int4*)deg)[b * 256 + tid];
    int t0 = v.x, t1 = t0 + v.y, t2 = t1 + v.z, t3 = t2 + v.w;
    s[tid] = t3;
    __syncthreads();
    for (int off = 1; off < 256; off <<= 1) {
        int x = (tid >= off) ? s[tid - off] : 0;
        __syncthreads();
        if (tid >= off) s[tid] += x;
        __syncthreads();
    }
    int excl = tid ? s[tid - 1] : 0;
    int4 o; o.x = excl; o.y = excl + t0; o.z = excl + t1; o.w = excl + t2;
    ((int4*)offs)[b * 256 + tid] = o;
    if (tid == 255) bsum[b] = s[255];
}

__global__ __launch_bounds__(128) void scan2(int* __restrict__ bsum)
{
    __shared__ int s[128];
    int tid = threadIdx.x;
    s[tid] = bsum[tid];
    __syncthreads();
    for (int off = 1; off < 128; off <<= 1) {
        int x = (tid >= off) ? s[tid - off] : 0;
        __syncthreads();
        if (tid >= off) s[tid] += x;
        __syncthreads();
    }
    bsum[tid] = tid ? s[tid - 1] : 0;
}

__global__ __launch_bounds__(256) void scan3(int* __restrict__ offs,
    const int* __restrict__ bsum, int* __restrict__ pos)
{
    int i = blockIdx.x * 256 + threadIdx.x;
    int v = offs[i] + bsum[i >> 10];
    offs[i] = v;
    pos[i] = v;
    if (i == 0) offs[NNODES] = NEDGES;
}

__global__ __launch_bounds__(256) void csr_fill(const int* __restrict__ src,
    const int* __restrict__ dst, const float* __restrict__ ew,
    int* __restrict__ pos, int2* __restrict__ csr)
{
    int e = blockIdx.x * 256 + threadIdx.x;
    int slot = atomicAdd(&pos[dst[e]], 1);
    csr[slot] = make_int2(src[e], __float_as_int(ew[e]));
}

// ---------------- gather aggregate (4-deep ILP): agg[n] = sum ew_e * h[src_e] ----
__global__ __launch_bounds__(256) void gather_agg(const _Float16* __restrict__ t,
    const int2* __restrict__ csr, const int* __restrict__ offs,
    _Float16* __restrict__ agg)
{
    int node = blockIdx.x * 4 + (threadIdx.x >> 6);
    int lane = threadIdx.x & 63;
    int i = offs[node], end = offs[node + 1];
    float a0 = 0.0f, a1 = 0.0f;
    for (; i + 4 <= end; i += 4) {
        int2 e0 = csr[i], e1 = csr[i + 1], e2 = csr[i + 2], e3 = csr[i + 3];
        half2v v0 = *(const half2v*)(t + (size_t)e0.x * 128 + lane * 2);
        half2v v1 = *(const half2v*)(t + (size_t)e1.x * 128 + lane * 2);
        half2v v2 = *(const half2v*)(t + (size_t)e2.x * 128 + lane * 2);
        half2v v3 = *(const half2v*)(t + (size_t)e3.x * 128 + lane * 2);
        float w0 = __int_as_float(e0.y), w1 = __int_as_float(e1.y);
        float w2 = __int_as_float(e2.y), w3 = __int_as_float(e3.y);
        a0 = fmaf((float)v0[0], w0, a0); a1 = fmaf((float)v0[1], w0, a1);
        a0 = fmaf((float)v1[0], w1, a0); a1 = fmaf((float)v1[1], w1, a1);
        a0 = fmaf((float)v2[0], w2, a0); a1 = fmaf((float)v2[1], w2, a1);
        a0 = fmaf((float)v3[0], w3, a0); a1 = fmaf((float)v3[1], w3, a1);
    }
    for (; i < end; ++i) {
        int2 e = csr[i];
        float w = __int_as_float(e.y);
        half2v v = *(const half2v*)(t + (size_t)e.x * 128 + lane * 2);
        a0 = fmaf((float)v[0], w, a0);
        a1 = fmaf((float)v[1], w, a1);
    }
    half2v o; o[0] = (_Float16)a0; o[1] = (_Float16)a1;
    *(half2v*)(agg + (size_t)node * 128 + lane * 2) = o;
}

// ---------------- emb1: x = relu(G @ W1 + b1) -> fp16 ----------------
__global__ __launch_bounds__(256) void emb1_kernel(const float* __restrict__ G,
    const float* __restrict__ W1, const float* __restrict__ b1, _Float16* __restrict__ Y)
{
    int idx = blockIdx.x * 256 + threadIdx.x;
    int n = idx >> 7, c = idx & 127;
    const float* g = G + (size_t)n * 8;
    float y = b1[c];
#pragma unroll
    for (int k = 0; k < 8; ++k) y = fmaf(g[k], W1[k * 128 + c], y);
    Y[(size_t)n * 128 + c] = (_Float16)fmaxf(y, 0.0f);
}

// ---------------- MFMA GEMM: out = act(X @ WtT + bias [+gproj]) ----------------
template<int K, int MCH, bool INF16, bool RELU, bool SEGADD>
__global__ __launch_bounds__(256, 2) void gemm_mfma(
    const void* __restrict__ Xin, int xstride,
    const _Float16* __restrict__ Wt,
    const float* __restrict__ bias,
    _Float16* __restrict__ out1, int ostride,
    const float* __restrict__ gproj, const int* __restrict__ seg)
{
    constexpr int ROWB = 2 * K;
    constexpr int SPR  = K / 8;
    __shared__ __align__(16) char Xs[128 * ROWB];
    __shared__ __align__(16) char Ws[128 * ROWB];
    const int tid = threadIdx.x, wid = tid >> 6, l = tid & 63;
    const int lr = l & 15, lk = l >> 4;
    const int wrow = wid * 32;

    for (int mc = 0; mc < MCH; ++mc) {
        __syncthreads();
        {
            const _Float16* wsrc = Wt + (size_t)mc * 128 * K;
            for (int s0 = wid * 64; s0 < 128 * SPR; s0 += 256) {
                int s = s0 + l;
                int row = s / SPR, sub = s % SPR;
                int ksub = sub ^ (row & 7);
                async16(Ws + s0 * 16, (const char*)(wsrc + (size_t)row * K) + ksub * 16);
            }
        }
        asm volatile("s_waitcnt vmcnt(0)" ::: "memory");
        __syncthreads();

        half8 bfr[32];
        if constexpr (K == 128) {
#pragma unroll
            for (int ct = 0; ct < 8; ++ct)
#pragma unroll
                for (int ks = 0; ks < 4; ++ks) {
                    int row = ct * 16 + lr;
                    bfr[ct * 4 + ks] = *(const half8*)(Ws + row * ROWB +
                        ((ks * 64 + lk * 16) ^ ((row & 7) << 4)));
                }
        }

        for (int t = blockIdx.x; t < NNODES / 128; t += gridDim.x) {
            const int nbase = t * 128;
            __syncthreads();
            if constexpr (INF16) {
                const _Float16* xsrc = (const _Float16*)Xin;
                for (int s0 = wid * 64; s0 < 128 * SPR; s0 += 256) {
                    int s = s0 + l;
                    int row = s / SPR, sub = s % SPR;
                    int ksub = sub ^ (row & 7);
                    async16(Xs + s0 * 16,
                            (const char*)(xsrc + (size_t)(nbase + row) * xstride) + ksub * 16);
                }
                asm volatile("s_waitcnt vmcnt(0)" ::: "memory");
            } else {
                const float* xsrc = (const float*)Xin;
                for (int s = tid; s < 128 * SPR; s += 256) {
                    int row = s / SPR, sub = s % SPR;
                    int ksub = sub ^ (row & 7);
                    const float* p = xsrc + (size_t)(nbase + row) * xstride + ksub * 8;
                    float4 u = ((const float4*)p)[0];
                    float4 v = ((const float4*)p)[1];
                    half8 hv;
                    hv[0] = (_Float16)u.x; hv[1] = (_Float16)u.y;
                    hv[2] = (_Float16)u.z; hv[3] = (_Float16)u.w;
                    hv[4] = (_Float16)v.x; hv[5] = (_Float16)v.y;
                    hv[6] = (_Float16)v.z; hv[7] = (_Float16)v.w;
                    *(half8*)(Xs + s * 16) = hv;
                }
            }
            __syncthreads();

            float4v acc[2][8];
#pragma unroll
            for (int i = 0; i < 2; ++i)
#pragma unroll
                for (int j = 0; j < 8; ++j)
#pragma unroll
                    for (int q = 0; q < 4; ++q) acc[i][j][q] = 0.0f;

            if constexpr (K == 128) {
#pragma unroll
                for (int rt = 0; rt < 2; ++rt) {
                    half8 a[4];
                    int row = wrow + rt * 16 + lr;
#pragma unroll
                    for (int ks = 0; ks < 4; ++ks)
                        a[ks] = *(const half8*)(Xs + row * ROWB +
                            ((ks * 64 + lk * 16) ^ ((row & 7) << 4)));
#pragma unroll
                    for (int ct = 0; ct < 8; ++ct)
#pragma unroll
                        for (int ks = 0; ks < 4; ++ks)
                            acc[rt][ct] = __builtin_amdgcn_mfma_f32_16x16x32_f16(
                                a[ks], bfr[ct * 4 + ks], acc[rt][ct], 0, 0, 0);
                }
            } else {   // K == 256
#pragma unroll
                for (int kc = 0; kc < 2; ++kc) {
#pragma unroll
                    for (int ct = 0; ct < 8; ++ct)
#pragma unroll
                        for (int ks = 0; ks < 4; ++ks) {
                            int row = ct * 16 + lr;
                            bfr[ct * 4 + ks] = *(const half8*)(Ws + row * ROWB +
                                (((kc * 4 + ks) * 64 + lk * 16) ^ ((row & 7) << 4)));
                        }
#pragma unroll
                    for (int rt = 0; rt < 2; ++rt) {
                        half8 a[4];
                        int row = wrow + rt * 16 + lr;
#pragma unroll
                        for (int ks = 0; ks < 4; ++ks)
                            a[ks] = *(const half8*)(Xs + row * ROWB +
                                (((kc * 4 + ks) * 64 + lk * 16) ^ ((row & 7) << 4)));
#pragma unroll
                        for (int ct = 0; ct < 8; ++ct)
#pragma unroll
                            for (int ks = 0; ks < 4; ++ks)
                                acc[rt][ct] = __builtin_amdgcn_mfma_f32_16x16x32_f16(
                                    a[ks], bfr[ct * 4 + ks], acc[rt][ct], 0, 0, 0);
                    }
                }
            }

#pragma unroll
            for (int rt = 0; rt < 2; ++rt)
#pragma unroll
            for (int ct = 0; ct < 8; ++ct) {
                const int col = ct * 16 + lr;
                float bv = 0.0f;
                if (bias) bv = bias[mc * 128 + col];
#pragma unroll
                for (int j = 0; j < 4; ++j) {
                    const int n = nbase + wrow + rt * 16 + lk * 4 + j;
                    float v = acc[rt][ct][j] + bv;
                    if constexpr (SEGADD)
                        v += gproj[(size_t)seg[n] * 256 + mc * 128 + col];
                    if constexpr (RELU) v = fmaxf(v, 0.0f);
                    out1[(size_t)n * ostride + mc * 128 + col] = (_Float16)v;
                }
            }
        }
    }
}

// ---------------- fully-fused GRU (combined input weight Wc = Wih*W^T) ----------
__global__ __launch_bounds__(512, 2) void gru_fused(
    const _Float16* __restrict__ agg,   // [N][128] = raw gathered h
    _Float16* h,                        // [N][128] in/out
    const _Float16* __restrict__ Wih,   // combined Wc fp16 [384][128]
    const _Float16* __restrict__ Whh,   // [384][128] fp16
    const float* __restrict__ bih, const float* __restrict__ bhh,
    int relu_out)
{
    __shared__ __align__(16) char As[128 * 256];
    __shared__ __align__(16) char Hs[128 * 256];
    __shared__ __align__(16) char Wb[2][128 * 256];
    const int tid = threadIdx.x, wid = tid >> 6, l = tid & 63;
    const int lr = l & 15, lk = l >> 4;
    const int wr = wid >> 1, wc = wid & 1;
    const int nbase = blockIdx.x * 128;

    auto stageT = [&](char* dst, const _Float16* src) {
        for (int s0 = wid * 64; s0 < 2048; s0 += 512) {
            int s = s0 + l;
            int row = s >> 4, sub = s & 15;
            int ksub = sub ^ (row & 7);
            async16(dst + s0 * 16, (const char*)(src + (size_t)row * 128) + ksub * 16);
        }
    };

    stageT(As, agg + (size_t)nbase * 128);
    stageT(Hs, h + (size_t)nbase * 128);
    stageT(Wb[0], Wih);

    float4v accA[2][4], accB[2][4], rg[2][4], zg[2][4];
    half8 aAg[2][4], aH[2][4];

#pragma unroll
    for (int c = 0; c < 6; ++c) {
        asm volatile("s_waitcnt vmcnt(0)" ::: "memory");
        __syncthreads();
        if (c < 5) {
            const int nc = c + 1;
            const _Float16* wsrc = ((nc & 1) ? Whh : Wih) + (size_t)(nc >> 1) * 16384;
            stageT(Wb[nc & 1], wsrc);
        }
        if (c == 0) {
#pragma unroll
            for (int rt = 0; rt < 2; ++rt) {
                const int row = wr * 32 + rt * 16 + lr;
#pragma unroll
                for (int ks = 0; ks < 4; ++ks) {
                    const int off = row * 256 + ((ks * 64 + lk * 16) ^ ((row & 7) << 4));
                    aAg[rt][ks] = *(const half8*)(As + off);
                    aH[rt][ks]  = *(const half8*)(Hs + off);
                }
            }
        }

        auto& af  = (c & 1) ? aH : aAg;
        auto& acc = (c & 1) ? accB : accA;
#pragma unroll
        for (int rt = 0; rt < 2; ++rt)
#pragma unroll
            for (int ct = 0; ct < 4; ++ct)
#pragma unroll
                for (int q = 0; q < 4; ++q) acc[rt][ct][q] = 0.0f;

        const char* wb = Wb[c & 1];
#pragma unroll
        for (int ct = 0; ct < 4; ++ct) {
            const int rowb = wc * 64 + ct * 16 + lr;
#pragma unroll
            for (int ks = 0; ks < 4; ++ks) {
                half8 b = *(const half8*)(wb + rowb * 256 +
                    ((ks * 64 + lk * 16) ^ ((rowb & 7) << 4)));
                acc[0][ct] = __builtin_amdgcn_mfma_f32_16x16x32_f16(af[0][ks], b, acc[0][ct], 0, 0, 0);
                acc[1][ct] = __builtin_amdgcn_mfma_f32_16x16x32_f16(af[1][ks], b, acc[1][ct], 0, 0, 0);
            }
        }

        if (c == 1) {
#pragma unroll
            for (int rt = 0; rt < 2; ++rt)
#pragma unroll
            for (int ct = 0; ct < 4; ++ct) {
                const int col = wc * 64 + ct * 16 + lr;
                const float bb = bih[col] + bhh[col];
#pragma unroll
                for (int j = 0; j < 4; ++j)
                    rg[rt][ct][j] = fsigm(accA[rt][ct][j] + accB[rt][ct][j] + bb);
            }
        } else if (c == 3) {
#pragma unroll
            for (int rt = 0; rt < 2; ++rt)
#pragma unroll
            for (int ct = 0; ct < 4; ++ct) {
                const int col = wc * 64 + ct * 16 + lr;
                const float bb = bih[128 + col] + bhh[128 + col];
#pragma unroll
                for (int j = 0; j < 4; ++j)
                    zg[rt][ct][j] = fsigm(accA[rt][ct][j] + accB[rt][ct][j] + bb);
            }
        } else if (c == 5) {
#pragma unroll
            for (int rt = 0; rt < 2; ++rt)
#pragma unroll
            for (int ct = 0; ct < 4; ++ct) {
                const int col = wc * 64 + ct * 16 + lr;
                const float bi = bih[256 + col], bh = bhh[256 + col];
                const int c2 = col * 2;
#pragma unroll
                for (int j = 0; j < 4; ++j) {
                    const int row = wr * 32 + rt * 16 + lk * 4 + j;
                    const int n = nbase + row;
                    float nv = ftanh(accA[rt][ct][j] + bi +
                                     rg[rt][ct][j] * (accB[rt][ct][j] + bh));
                    float hold = (float)*(const _Float16*)(Hs + row * 256 +
                        (((c2 >> 4) ^ (row & 7)) << 4) + (c2 & 15));
                    float z = zg[rt][ct][j];
                    float hn = (1.0f - z) * nv + z * hold;
                    if (relu_out) hn = fmaxf(hn, 0.0f);
                    h[(size_t)n * 128 + col] = (_Float16)hn;
                }
            }
        }
    }
}

// ---------------- segment sums (seg sorted) ----------------
__global__ __launch_bounds__(256) void seg_sum(const _Float16* __restrict__ x,
    const int* __restrict__ seg, float* __restrict__ sums, float* __restrict__ counts)
{
    int cg = threadIdx.x & 31, rs = threadIdx.x >> 5;
    int r0 = blockIdx.x * 256 + rs * 32;
    float a0 = 0, a1 = 0, a2 = 0, a3 = 0, cnt = 0;
    int cur = seg[r0];
    for (int i = 0; i < 32; ++i) {
        int n = r0 + i;
        int p = seg[n];
        if (p != cur) {
            atomicAdd(&sums[(size_t)cur * 128 + cg * 4 + 0], a0);
            atomicAdd(&sums[(size_t)cur * 128 + cg * 4 + 1], a1);
            atomicAdd(&sums[(size_t)cur * 128 + cg * 4 + 2], a2);
            atomicAdd(&sums[(size_t)cur * 128 + cg * 4 + 3], a3);
            if (cg == 0) atomicAdd(&counts[cur], cnt);
            a0 = a1 = a2 = a3 = 0; cnt = 0; cur = p;
        }
        half4v v = *(const half4v*)(x + (size_t)n * 128 + cg * 4);
        a0 += (float)v[0]; a1 += (float)v[1]; a2 += (float)v[2]; a3 += (float)v[3];
        cnt += 1.0f;
    }
    atomicAdd(&sums[(size_t)cur * 128 + cg * 4 + 0], a0);
    atomicAdd(&sums[(size_t)cur * 128 + cg * 4 + 1], a1);
    atomicAdd(&sums[(size_t)cur * 128 + cg * 4 + 2], a2);
    atomicAdd(&sums[(size_t)cur * 128 + cg * 4 + 3], a3);
    if (cg == 0) atomicAdd(&counts[cur], cnt);
}

// ---------------- gproj2[p][m] = cvec[m] + sum_t ymean[t]*Bf[t][m] ----------------
__global__ __launch_bounds__(256) void gproj2_kernel(const float* __restrict__ sums,
    const float* __restrict__ counts, const float* __restrict__ Bf,
    const float* __restrict__ cvec, float* __restrict__ gproj2)
{
    __shared__ float gm[128];
    int p = blockIdx.x, m = threadIdx.x;
    if (m < 128) gm[m] = sums[(size_t)p * 128 + m] / fmaxf(counts[p], 1.0f);
    __syncthreads();
    float acc = cvec[m];
#pragma unroll 8
    for (int k = 0; k < 128; ++k)
        acc = fmaf(gm[k], Bf[(size_t)k * 256 + m], acc);
    gproj2[(size_t)p * 256 + m] = acc;
}

// ---------------- final: out[n] = u2[n] . W_l3 + b_l3 ----------------
__global__ __launch_bounds__(256) void final_dot(const _Float16* __restrict__ u2,
    const float* __restrict__ wl3, const float* __restrict__ bl3, float* __restrict__ out)
{
    int gid = blockIdx.x * 256 + threadIdx.x;
    int n = gid >> 6, lane = gid & 63;
    half2v v = *(const half2v*)(u2 + (size_t)n * 128 + lane * 2);
    float s = (float)v[0] * wl3[lane * 2] + (float)v[1] * wl3[lane * 2 + 1];
#pragma unroll
    for (int off = 32; off; off >>= 1) s += __shfl_xor(s, off);
    if (lane == 0) out[n] = s + bl3[0];
}

extern "C" void kernel_launch(void* const* d_in, const int* in_sizes, int n_in,
                              void* d_out, int out_size, void* d_ws, size_t ws_size,
                              hipStream_t stream)
{
    (void)in_sizes; (void)n_in; (void)out_size; (void)ws_size;

    const float* G     = (const float*)d_in[0];
    const int*   ei    = (const int*)d_in[1];
    const float* ew    = (const float*)d_in[2];
    const int*   seg   = (const int*)d_in[4];
    const float* Wemb1 = (const float*)d_in[5];  const float* bemb1 = (const float*)d_in[6];
    const float* Wemb2 = (const float*)d_in[7];  const float* bemb2 = (const float*)d_in[8];
    const float* c1W   = (const float*)d_in[9];
    const float* c1Wih = (const float*)d_in[10]; const float* c1Whh = (const float*)d_in[11];
    const float* c1bih = (const float*)d_in[12]; const float* c1bhh = (const float*)d_in[13];
    const float* c2W   = (const float*)d_in[14];
    const float* c2Wih = (const float*)d_in[15]; const float* c2Whh = (const float*)d_in[16];
    const float* c2bih = (const float*)d_in[17]; const float* c2bhh = (const float*)d_in[18];
    const float* Wg1   = (const float*)d_in[19]; const float* bg1   = (const float*)d_in[20];
    const float* Wg2   = (const float*)d_in[21]; const float* bg2   = (const float*)d_in[22];
    const float* Wl    = (const float*)d_in[23]; const float* bl    = (const float*)d_in[24];
    const float* Wl2   = (const float*)d_in[25]; const float* bl2   = (const float*)d_in[26];
    const float* Wl3   = (const float*)d_in[27]; const float* bl3   = (const float*)d_in[28];

    const int* srcp = ei;
    const int* dstp = ei + NEDGES;

    char* ws = (char*)d_ws;
    const size_t NBH = (size_t)NNODES * 128 * 2;   // 32MB
    const size_t U1B = (size_t)NNODES * 256 * 2;   // 64MB

    _Float16* hA   = (_Float16*)ws;                 // h / x
    _Float16* hB   = (_Float16*)(ws + NBH);         // y / u2
    _Float16* u1   = (_Float16*)(ws + 2 * NBH);     // [N][256]
    _Float16* aggH = (_Float16*)(ws + 2 * NBH + U1B);
    char*     aux  = ws + 3 * NBH + U1B;
    float* sums    = (float*)aux;                    // 32KB
    float* counts  = (float*)(aux + 32768);          // 1KB
    float* gproj2  = (float*)(aux + 33792);          // 64KB
    int*   deg     = (int*)(aux + 33792 + 65536);
    int*   offs    = deg + NNODES;
    int*   pos     = offs + NNODES + 64;
    int2*  csr     = (int2*)(pos + NNODES);
    char*  wtb     = (char*)csr + (size_t)NEDGES * 8;

    _Float16* wt_emb2 = (_Float16*)wtb;                    // [128][128]
    _Float16* wt_g1   = wt_emb2 + 16384;                   // [128][128]
    _Float16* wt_l2   = wt_g1 + 16384;                     // [128][256] (M=128,K=256)
    _Float16* wt_hh1  = wt_l2 + 32768;                     // [384][128]
    _Float16* wt_hh2  = wt_hh1 + 49152;
    _Float16* wc00    = wt_hh2 + 49152;                    // combined Wih*W^T per (cv,l)
    _Float16* wc01    = wc00 + 49152;
    _Float16* wc10    = wc01 + 49152;
    _Float16* wc11    = wc10 + 49152;
    _Float16* At      = wc11 + 49152;                      // [256][128]
    float*    Bf      = (float*)(At + 32768);              // [128][256] fp32
    float*    cvec    = Bf + 32768;                        // [256]

    // ---- weight prep ----
    tr_cvt<<<64, 256, 0, stream>>>(Wemb2, wt_emb2, 128, 128, 128);
    tr_cvt<<<64, 256, 0, stream>>>(Wg1, wt_g1, 128, 128, 128);
    tr_cvt<<<128, 256, 0, stream>>>(Wl2, wt_l2, 256, 128, 128);
    cvt16<<<192, 256, 0, stream>>>(c1Whh, wt_hh1, 49152);
    cvt16<<<192, 256, 0, stream>>>(c2Whh, wt_hh2, 49152);
    combine_gru<<<192, 256, 0, stream>>>(c1Wih, c1W,         wc00);
    combine_gru<<<192, 256, 0, stream>>>(c1Wih, c1W + 16384, wc01);
    combine_gru<<<192, 256, 0, stream>>>(c2Wih, c2W,         wc10);
    combine_gru<<<192, 256, 0, stream>>>(c2Wih, c2W + 16384, wc11);
    combine_headA<<<128, 256, 0, stream>>>(Wg2, Wl, At);
    combine_headB<<<128, 256, 0, stream>>>(Wg2, Wl, Bf);
    combine_c<<<1, 256, 0, stream>>>(bg2, Wl, bl, cvec);

    // ---- CSR build ----
    hipMemsetAsync(deg, 0, NNODES * 4, stream);
    deg_hist<<<NEDGES / 256, 256, 0, stream>>>(dstp, deg);
    scan1<<<128, 256, 0, stream>>>(deg, offs, pos);
    scan2<<<1, 128, 0, stream>>>(pos);
    scan3<<<NNODES / 256, 256, 0, stream>>>(offs, pos, deg);
    csr_fill<<<NEDGES / 256, 256, 0, stream>>>(srcp, dstp, ew, deg, csr);

    // ---- embeddings ----
    emb1_kernel<<<NNODES * 128 / 256, 256, 0, stream>>>(G, Wemb1, bemb1, hB);
    gemm_mfma<128, 1, true, true, false><<<512, 256, 0, stream>>>(
        hB, 128, wt_emb2, bemb2, hA, 128, nullptr, nullptr);

    // ---- 2 GatedGraphConv layers x 2 GRU iterations (conv GEMM folded into Wc) --
    const _Float16* wcs[2][2] = { { wc00, wc01 }, { wc10, wc11 } };
    const _Float16* whh[2] = { wt_hh1, wt_hh2 };
    const float* bihs[2] = { c1bih, c2bih };
    const float* bhhs[2] = { c1bhh, c2bhh };
    for (int cv = 0; cv < 2; ++cv) {
        for (int lyr = 0; lyr < 2; ++lyr) {
            gather_agg<<<NNODES / 4, 256, 0, stream>>>(hA, csr, offs, aggH);
            gru_fused<<<NNODES / 128, 512, 0, stream>>>(
                aggH, hA, wcs[cv][lyr], whh[cv], bihs[cv], bhhs[cv], (lyr == 1) ? 1 : 0);
        }
    }

    // ---- head: y = relu(x@Wg1+bg1); Wg2 folded into At/Bf/cvec ----
    gemm_mfma<128, 1, true, true, false><<<512, 256, 0, stream>>>(
        hA, 128, wt_g1, bg1, hB, 128, nullptr, nullptr);

    hipMemsetAsync(sums, 0, 33792, stream);
    seg_sum<<<NNODES / 256, 256, 0, stream>>>(hB, seg, sums, counts);
    gproj2_kernel<<<NPROB, 256, 0, stream>>>(sums, counts, Bf, cvec, gproj2);

    // ---- u1 = relu(y @ At^T + gproj2[seg]) [N,256] ----
    gemm_mfma<128, 2, true, true, true><<<512, 256, 0, stream>>>(
        hB, 128, At, nullptr, u1, 256, gproj2, seg);
    // ---- u2 = relu(u1 @ W_l2 + b_l2) [N,128] ----
    gemm_mfma<256, 1, true, true, false><<<256, 256, 0, stream>>>(
        u1, 256, wt_l2, bl2, hA, 128, nullptr, nullptr);
    // ---- out ----
    final_dot<<<NNODES * 64 / 256, 256, 0, stream>>>(hA, Wl3, bl3, (float*)d_out);
}